// Round 18
// baseline (3053.905 us; speedup 1.0000x reference)
//
#include <hip/hip_runtime.h>
#include <stdint.h>

typedef __bf16 bf16_t;
typedef bf16_t bf16x8 __attribute__((ext_vector_type(8)));
typedef float f32x4 __attribute__((ext_vector_type(4)));

__device__ __forceinline__ float bf2f(unsigned short u) {
  union { unsigned int i; float f; } x; x.i = ((unsigned int)u) << 16; return x.f;
}
__device__ __forceinline__ unsigned short f2bf(float f) {
  union { float f; unsigned int i; } x; x.f = f;
  unsigned int r = x.i + 0x7FFFu + ((x.i >> 16) & 1u);
  return (unsigned short)(r >> 16);
}
__device__ __forceinline__ unsigned pack2(float a, float b) {
  return (unsigned)f2bf(a) | ((unsigned)f2bf(b) << 16);
}

__global__ void cat3(const float* __restrict__ a, const float* __restrict__ b,
                     const float* __restrict__ c, float* __restrict__ dst) {
  int i = threadIdx.x;
  dst[i] = a[i]; dst[256 + i] = b[i]; dst[512 + i] = c[i];
}

__global__ __launch_bounds__(256) void wsplit(
    const float* __restrict__ in, unsigned short* __restrict__ hi,
    unsigned short* __restrict__ lo, int n) {
  int i = (blockIdx.x * 256 + threadIdx.x) * 8;
  if (i >= n) return;
  float4 a = *(const float4*)(in + i);
  float4 b = *(const float4*)(in + i + 4);
  float f[8] = {a.x, a.y, a.z, a.w, b.x, b.y, b.z, b.w};
  unsigned short sh[8], sl[8];
#pragma unroll
  for (int j = 0; j < 8; ++j) {
    sh[j] = f2bf(f[j]);
    sl[j] = f2bf(f[j] - bf2f(sh[j]));
  }
  *(uint4*)(hi + i) = *(uint4*)sh;
  *(uint4*)(lo + i) = *(uint4*)sl;
}

struct f8 { float4 a, b; };

__device__ __forceinline__ f8 ld_c8(const float* __restrict__ X,
                                    const float* __restrict__ TE,
                                    const float* __restrict__ SE,
                                    size_t row, int cc) {
  const float* src = (cc < 256) ? X : ((cc < 512) ? TE : SE);
  const float* p = src + row * 256 + (cc & 255);
  f8 r; r.a = *(const float4*)p; r.b = *(const float4*)(p + 4);
  return r;
}
__device__ __forceinline__ uint4 pack_hi(const float4 a, const float4 b) {
  return make_uint4(pack2(a.x, a.y), pack2(a.z, a.w), pack2(b.x, b.y), pack2(b.z, b.w));
}

// ---------- gemm7: A-panel-resident GEMM, 8 waves, 32 cols/wave, BM rows ----
// A panel staged to LDS once (bf16 hi, XOR-swizzled); column pass = 256 cols
// (wave strips at +0/+128); B in registers, 128-K batches; no K-loop barriers.
// BM=32 halves LDS (K=768: 58 KB -> 2 blocks/CU, 4 waves/SIMD).
// AMODE 0: A fp32. 1: A concat(X,TE,SE) fp32. 2: A bf16 raw.
// PREC 1: hi only. 2: hi+lo. 3: lo for strips >=256 (kv1: v1 cols).
//      4: lo for strips in [256,512) (fused kvq: v0 cols).
// SMODE 0: none, 1: raw bf16, 2: relu(BN) bf16,
//   5: dual raw bf16 (strip<256 -> Cb else Cb2, both stride 256),
//   6: tri raw bf16 (strip<512 -> Cb stride 512; else Cb2 stride 256).
// PART: per-block column partials (width Cout); cstr = C row stride.
template<int AMODE, int SMODE, int PART, int PREC, int K, int BM>
__global__ __launch_bounds__(512) void gemm7(
    const void* __restrict__ Ap, const float* __restrict__ AX,
    const float* __restrict__ ATE, const float* __restrict__ ASE,
    const unsigned short* __restrict__ Wh, const unsigned short* __restrict__ Wl,
    const float* __restrict__ bias, const float2* __restrict__ ssO,
    unsigned short* __restrict__ Cb, unsigned short* __restrict__ Cb2,
    float* __restrict__ psum, float* __restrict__ psq,
    int Cout, int cstr, int pOff, int nx) {
  constexpr int ASH = BM * K;
  constexpr int TOT = ASH + (SMODE != 0 ? BM * 136 : 8);
  constexpr int NC = K / 128;
  constexpr int MR = BM / 16;
  __shared__ unsigned short lds[TOT];
  unsigned short* lA = lds;
  unsigned short* lC = lds + ASH;

  const int tid = threadIdx.x;
  const int lane = tid & 63, wid = tid >> 6;
  const int l15 = lane & 15, l4 = lane >> 4;
  const int brow = blockIdx.x * BM;

  constexpr int CPR = K / 8;
#pragma unroll
  for (int i = 0; i < (BM * CPR) / 512; ++i) {
    int ch = i * 512 + tid;
    int row = ch / CPR, c8 = (ch % CPR) * 8;
    uint4 hv;
    if constexpr (AMODE == 2) {
      hv = *(const uint4*)((const unsigned short*)Ap + (size_t)(brow + row) * K + c8);
    } else if constexpr (AMODE == 0) {
      const float* p = (const float*)Ap + (size_t)(brow + row) * K + c8;
      hv = pack_hi(*(const float4*)p, *(const float4*)(p + 4));
    } else {
      f8 v = ld_c8(AX, ATE, ASE, (size_t)(brow + row), c8);
      hv = pack_hi(v.a, v.b);
    }
    int dst = row * K + (c8 & ~63) + ((c8 & 63) ^ ((row & 7) << 3));
    *(uint4*)(lA + dst) = hv;
  }
  __syncthreads();

  const int axor = (l15 & 7) << 3;
  const int colL = wid * 16 + l15;

  for (int cx = 0; cx < nx; ++cx) {
    const int bcol = cx * 256;
    const int bcs0 = bcol, bcs1 = bcol + 128;
    const bool lo0 = (PREC == 2) || (PREC == 3 && bcs0 >= 256) ||
                     (PREC == 4 && bcs0 >= 256 && bcs0 < 512);
    const bool lo1 = (PREC == 2) || (PREC == 3 && bcs1 >= 256) ||
                     (PREC == 4 && bcs1 >= 256 && bcs1 < 512);
    const unsigned short* wH0 = Wh + (size_t)(bcol + colL) * K + l4 * 8;
    const unsigned short* wH1 = wH0 + (size_t)128 * K;
    const unsigned short* wL0 = nullptr;
    const unsigned short* wL1 = nullptr;
    if constexpr (PREC >= 2) {
      wL0 = Wl + (size_t)(bcol + colL) * K + l4 * 8;
      wL1 = wL0 + (size_t)128 * K;
    }
    f32x4 acc[MR][2] = {};

#pragma unroll
    for (int c = 0; c < NC; ++c) {
      uint4 bh0[4], bh1[4], bl0[4], bl1[4];
#pragma unroll
      for (int ks = 0; ks < 4; ++ks) {
        bh0[ks] = *(const uint4*)(wH0 + c * 128 + ks * 32);
        bh1[ks] = *(const uint4*)(wH1 + c * 128 + ks * 32);
      }
      if constexpr (PREC >= 2) {
        if (lo0) {
#pragma unroll
          for (int ks = 0; ks < 4; ++ks) bl0[ks] = *(const uint4*)(wL0 + c * 128 + ks * 32);
        }
        if (lo1) {
#pragma unroll
          for (int ks = 0; ks < 4; ++ks) bl1[ks] = *(const uint4*)(wL1 + c * 128 + ks * 32);
        }
      }
#pragma unroll
      for (int kk = 0; kk < 4; ++kk) {
        const int kabs = c * 128 + kk * 32;
        const int kt64 = kabs & ~63;
        const int cofs = ((kabs & 32) + l4 * 8) ^ axor;
        bf16x8 af[MR];
#pragma unroll
        for (int m = 0; m < MR; ++m)
          af[m] = *(const bf16x8*)(lA + (m * 16 + l15) * K + kt64 + cofs);
        bf16x8 b0 = *(const bf16x8*)&bh0[kk];
        bf16x8 b1 = *(const bf16x8*)&bh1[kk];
#pragma unroll
        for (int m = 0; m < MR; ++m) {
          acc[m][0] = __builtin_amdgcn_mfma_f32_16x16x32_bf16(af[m], b0, acc[m][0], 0, 0, 0);
          acc[m][1] = __builtin_amdgcn_mfma_f32_16x16x32_bf16(af[m], b1, acc[m][1], 0, 0, 0);
        }
        if constexpr (PREC >= 2) {
          if (lo0) {
            bf16x8 c0 = *(const bf16x8*)&bl0[kk];
#pragma unroll
            for (int m = 0; m < MR; ++m)
              acc[m][0] = __builtin_amdgcn_mfma_f32_16x16x32_bf16(af[m], c0, acc[m][0], 0, 0, 0);
          }
          if (lo1) {
            bf16x8 c1 = *(const bf16x8*)&bl1[kk];
#pragma unroll
            for (int m = 0; m < MR; ++m)
              acc[m][1] = __builtin_amdgcn_mfma_f32_16x16x32_bf16(af[m], c1, acc[m][1], 0, 0, 0);
          }
        }
      }
    }

#pragma unroll
    for (int s = 0; s < 2; ++s) {
      const int bcs = bcol + s * 128;
      const int col = bcs + colL;
      float cs = 0.f, cq = 0.f;
      float bv = bias[col];
      float2 s2 = make_float2(1.f, 0.f);
      if constexpr (SMODE == 2) s2 = ssO[col];
      if constexpr (SMODE != 0) __syncthreads();
#pragma unroll
      for (int m = 0; m < MR; ++m) {
#pragma unroll
        for (int r = 0; r < 4; ++r) {
          float v = acc[m][s][r] + bv;
          if constexpr (PART) { cs += v; cq += v * v; }
          if constexpr (SMODE == 2) v = fmaxf(v * s2.x + s2.y, 0.f);
          if constexpr (SMODE != 0) lC[(m * 16 + l4 * 4 + r) * 136 + colL] = f2bf(v);
        }
      }
      if constexpr (SMODE != 0) {
        __syncthreads();
        const int rw = tid >> 4, c16 = (tid & 15) * 8;
#pragma unroll
        for (int it = 0; it < BM / 32; ++it) {
          int rr = it * 32 + rw;
          uint4 val = *(const uint4*)(lC + rr * 136 + c16);
          if constexpr (SMODE == 5) {
            unsigned short* dst = (bcs < 256) ? Cb : Cb2;
            *(uint4*)(dst + (size_t)(brow + rr) * 256 + (bcs & 255) + c16) = val;
          } else if constexpr (SMODE == 6) {
            if (bcs < 512)
              *(uint4*)(Cb + (size_t)(brow + rr) * 512 + bcs + c16) = val;
            else
              *(uint4*)(Cb2 + (size_t)(brow + rr) * 256 + (bcs - 512) + c16) = val;
          } else {
            *(uint4*)(Cb + (size_t)(brow + rr) * cstr + bcs + c16) = val;
          }
        }
      }
      if constexpr (PART) {
        cs += __shfl_xor(cs, 16); cs += __shfl_xor(cs, 32);
        cq += __shfl_xor(cq, 16); cq += __shfl_xor(cq, 32);
        if (l4 == 0) {
          size_t pidx = (size_t)(pOff + blockIdx.x) * Cout + col;
          psum[pidx] = cs;
          psq[pidx]  = cq;
        }
      }
    }
  }
}

// ---------- column stats of a bf16 [rows][256] tensor; 2048 rows/block ----------
__global__ __launch_bounds__(256) void colstats(
    const unsigned short* __restrict__ A, float* __restrict__ psum,
    float* __restrict__ psq) {
  const int tid = threadIdx.x;
  const int r8 = tid >> 5, co = tid & 31;
  float s[8] = {0,0,0,0,0,0,0,0}, q[8] = {0,0,0,0,0,0,0,0};
  size_t base = (size_t)blockIdx.x * 2048;
  for (int it = 0; it < 256; ++it) {
    size_t row = base + it * 8 + r8;
    uint4 v = *(const uint4*)(A + row * 256 + co * 8);
    const unsigned short* pv = (const unsigned short*)&v;
#pragma unroll
    for (int j = 0; j < 8; ++j) {
      float f = bf2f(pv[j]);
      s[j] += f; q[j] += f * f;
    }
  }
  __shared__ float ls[8][32][8], lq[8][32][8];
#pragma unroll
  for (int j = 0; j < 8; ++j) { ls[r8][co][j] = s[j]; lq[r8][co][j] = q[j]; }
  __syncthreads();
  int co2 = tid >> 3, j2 = tid & 7;
  float S = 0.f, Q = 0.f;
#pragma unroll
  for (int r = 0; r < 8; ++r) { S += ls[r][co2][j2]; Q += lq[r][co2][j2]; }
  psum[(size_t)blockIdx.x * 256 + co2 * 8 + j2] = S;
  psq [(size_t)blockIdx.x * 256 + co2 * 8 + j2] = Q;
}

// ---------- BN stats: row-parallel partial + finalize ----------
__global__ __launch_bounds__(512) void bn_part(
    const float* __restrict__ psum, const float* __restrict__ psq,
    float* __restrict__ pp, int gridM, int Cout) {
  const int lane = threadIdx.x & 63, wv = threadIdx.x >> 6;
  const int c = blockIdx.y * 64 + lane;
  float s = 0.f, q = 0.f;
  for (int r = blockIdx.x + 64 * wv; r < gridM; r += 512) {
    s += psum[(size_t)r * Cout + c];
    q += psq[(size_t)r * Cout + c];
  }
  __shared__ float rs[8][64], rq[8][64];
  rs[wv][lane] = s; rq[wv][lane] = q;
  __syncthreads();
  if (threadIdx.x < 64) {
    float S = 0.f, Q = 0.f;
#pragma unroll
    for (int w2 = 0; w2 < 8; ++w2) { S += rs[w2][threadIdx.x]; Q += rq[w2][threadIdx.x]; }
    pp[(size_t)blockIdx.x * Cout + blockIdx.y * 64 + threadIdx.x] = S;
    pp[(size_t)(64 + blockIdx.x) * Cout + blockIdx.y * 64 + threadIdx.x] = Q;
  }
}
__global__ __launch_bounds__(64) void bn_fin(
    const float* __restrict__ pp, const float* __restrict__ g,
    const float* __restrict__ be, float2* __restrict__ ss,
    int CoutT, int colOff, float invR) {
  int c = blockIdx.x * 64 + threadIdx.x;
  int cp = colOff + c;
  float S = 0.f, Q = 0.f;
  for (int r = 0; r < 64; ++r) {
    S += pp[(size_t)r * CoutT + cp];
    Q += pp[(size_t)(64 + r) * CoutT + cp];
  }
  float mu = S * invR, var = Q * invR - mu * mu;
  float sc = g[c] * rsqrtf(var + 1e-5f);
  ss[c] = make_float2(sc, be[c] - mu * sc);
}
__global__ __launch_bounds__(64) void bn_fin2(
    const float* __restrict__ pp, const float* __restrict__ gA,
    const float* __restrict__ zA, const float* __restrict__ gB,
    const float* __restrict__ zB, float2* __restrict__ ssC,
    int CoutT, float invR) {
  int c = blockIdx.x * 64 + threadIdx.x;
  float S = 0.f, Q = 0.f;
  for (int r = 0; r < 64; ++r) {
    S += pp[(size_t)r * CoutT + c];
    Q += pp[(size_t)(64 + r) * CoutT + c];
  }
  float mu = S * invR, var = Q * invR - mu * mu;
  const float* g = (c < 256) ? gA : gB;
  const float* z = (c < 256) ? zA : zB;
  int ci = c & 255;
  float sc = g[ci] * rsqrtf(var + 1e-5f);
  ssC[c] = make_float2(sc, z[ci] - mu * sc);
}

// ---------- attention: q bf16 (+BN), k/v bf16 (+BN), bf16 out ----------
template<int NK, int NQ>
__global__ void attn_sm(const unsigned short* __restrict__ qy,
                        const unsigned short* __restrict__ ky,
                        const unsigned short* __restrict__ vy,
                        const float2* __restrict__ ssq, const float2* __restrict__ ssk,
                        const float2* __restrict__ ssv, unsigned short* __restrict__ out,
                        size_t qStride, size_t kvStride, size_t oStride, int RS) {
  __shared__ float kl[NK][16][17];
  __shared__ float vl[NK][16][17];
  const int n = blockIdx.x, b = blockIdx.y;
  const int tid = threadIdx.x;
  const unsigned short* kyb = ky + (size_t)b * kvStride;
  const unsigned short* vyb = vy + (size_t)b * kvStride;
  for (int ch = tid; ch < NK * 32; ch += NQ * 16) {
    int t = ch >> 5, c8 = (ch & 31) * 8;
    size_t src = ((size_t)t * 500 + n) * RS + c8;
    uint4 kv = *(const uint4*)(kyb + src);
    uint4 vv = *(const uint4*)(vyb + src);
    const unsigned short* kp = (const unsigned short*)&kv;
    const unsigned short* vp = (const unsigned short*)&vv;
#pragma unroll
    for (int j = 0; j < 8; ++j) {
      int c = c8 + j;
      float2 sk = ssk[c], sv = ssv[c];
      kl[t][c >> 4][c & 15] = fmaxf(bf2f(kp[j]) * sk.x + sk.y, 0.f);
      vl[t][c >> 4][c & 15] = fmaxf(bf2f(vp[j]) * sv.x + sv.y, 0.f);
    }
  }
  __syncthreads();
  const int s = tid >> 4, h = tid & 15;
  unsigned short qraw[16];
  size_t qb = (size_t)b * qStride + ((size_t)s * 500 + n) * 256 + h * 16;
  *(uint4*)qraw = *(const uint4*)(qy + qb);
  *(uint4*)(qraw + 8) = *(const uint4*)(qy + qb + 8);
  float qv[16];
#pragma unroll
  for (int c = 0; c < 16; ++c) {
    float2 sq = ssq[h * 16 + c];
    qv[c] = fmaxf(bf2f(qraw[c]) * sq.x + sq.y, 0.f);
  }
  float lg[NK], mx = -1e30f;
#pragma unroll
  for (int t = 0; t < NK; ++t) {
    float d = 0.f;
#pragma unroll
    for (int c = 0; c < 16; ++c) d += qv[c] * kl[t][h][c];
    lg[t] = d * 0.25f;
    mx = fmaxf(mx, lg[t]);
  }
  float sum = 0.f;
#pragma unroll
  for (int t = 0; t < NK; ++t) { lg[t] = __expf(lg[t] - mx); sum += lg[t]; }
  float inv = 1.f / sum;
  float o[16];
#pragma unroll
  for (int c = 0; c < 16; ++c) o[c] = 0.f;
#pragma unroll
  for (int t = 0; t < NK; ++t) {
    float p = lg[t] * inv;
#pragma unroll
    for (int c = 0; c < 16; ++c) o[c] += p * vl[t][h][c];
  }
  size_t ob = (size_t)b * oStride + ((size_t)s * 500 + n) * 256 + h * 16;
  uint4 w0;
  w0.x = pack2(o[0], o[1]); w0.y = pack2(o[2], o[3]);
  w0.z = pack2(o[4], o[5]); w0.w = pack2(o[6], o[7]);
  *(uint4*)(out + ob) = w0;
  w0.x = pack2(o[8], o[9]); w0.y = pack2(o[10], o[11]);
  w0.z = pack2(o[12], o[13]); w0.w = pack2(o[14], o[15]);
  *(uint4*)(out + ob + 8) = w0;
}

// ---------- final: out = X + relu(BN(y)), y bf16 ----------
__global__ __launch_bounds__(256) void bn_relu_addx(
    const unsigned short* __restrict__ y, const float2* __restrict__ ss,
    const float* __restrict__ X, float* __restrict__ out) {
  int r = blockIdx.x * 8 + (threadIdx.x >> 5);
  int c8 = (threadIdx.x & 31) * 8;
  size_t idx = (size_t)r * 256 + c8;
  uint4 yv4 = *(const uint4*)(y + idx);
  const unsigned short* yv = (const unsigned short*)&yv4;
  float4 x0 = *(const float4*)(X + idx);
  float4 x1 = *(const float4*)(X + idx + 4);
  float ov[8];
#pragma unroll
  for (int j = 0; j < 8; ++j) {
    float2 sc = ss[c8 + j];
    ov[j] = fmaxf(bf2f(yv[j]) * sc.x + sc.y, 0.f);
  }
  *(float4*)(out + idx)     = make_float4(x0.x + ov[0], x0.y + ov[1], x0.z + ov[2], x0.w + ov[3]);
  *(float4*)(out + idx + 4) = make_float4(x1.x + ov[4], x1.y + ov[5], x1.z + ov[6], x1.w + ov[7]);
}

// ---------- launcher ----------
extern "C" void kernel_launch(void* const* d_in, const int* in_sizes, int n_in,
                              void* d_out, int out_size, void* d_ws, size_t ws_size,
                              hipStream_t stream) {
  (void)in_sizes; (void)n_in; (void)out_size; (void)ws_size;
  const float* X  = (const float*)d_in[0];
  const float* TE = (const float*)d_in[1];
  const float* SE = (const float*)d_in[2];
  const float* I  = (const float*)d_in[3];
  const float *Wf[8], *Bf[8], *Gf[8], *Zf[8];
  for (int l = 0; l < 8; ++l) {
    Wf[l] = (const float*)d_in[4 + l * 4 + 0];
    Bf[l] = (const float*)d_in[4 + l * 4 + 1];
    Gf[l] = (const float*)d_in[4 + l * 4 + 2];
    Zf[l] = (const float*)d_in[4 + l * 4 + 3];
  }

  char* w = (char*)d_ws;
  size_t off = 0;
  auto alloc = [&](size_t bytes) -> void* {
    void* p = w + off;
    off += (bytes + 255) & ~(size_t)255;
    return p;
  };

  // ---- workspace (~342 MB; ws >= 345 MB proven) ----
  float* psum0 = (float*)alloc((size_t)4000 * 768 * 4);
  float* psq0  = (float*)alloc((size_t)4000 * 768 * 4);
  float* psumK = (float*)alloc((size_t)125 * 256 * 4);
  float* psqK  = (float*)alloc((size_t)125 * 256 * 4);
  float* pp    = (float*)alloc((size_t)128 * 768 * 4);
  float2* ss   = (float2*)alloc((size_t)(8 * 768 + 512) * sizeof(float2));
  float2* ssC  = ss + 8 * 768;
  unsigned short *W0h, *W0l, *W3h, *W3l, *W7h, *W7l;
  unsigned short *KVQh, *KVQl, *KV1h, *KV1l;
  W0h = (unsigned short*)alloc(196608 * 2); W0l = (unsigned short*)alloc(196608 * 2);
  W3h = (unsigned short*)alloc(196608 * 2); W3l = (unsigned short*)alloc(196608 * 2);
  W7h = (unsigned short*)alloc(65536 * 2);  W7l = (unsigned short*)alloc(65536 * 2);
  KVQh = (unsigned short*)alloc(589824 * 2); KVQl = (unsigned short*)alloc(589824 * 2);
  KV1h = (unsigned short*)alloc(393216 * 2); KV1l = (unsigned short*)alloc(393216 * 2);
  float* b124 = (float*)alloc(768 * 4);
  float* b56  = (float*)alloc(512 * 4);
  // region R: q0 | kv0 | pad  == exactly k1 [256000][256] bf16 later
  char* R = (char*)alloc(131072000);
  unsigned short* q0  = (unsigned short*)R;                    // 16000*256
  unsigned short* kv0 = (unsigned short*)(R + 8192000);        // 96000*512
  unsigned short* k1  = (unsigned short*)R;                    // 256000*256
  unsigned short* o0b = (unsigned short*)alloc(131072000);     // 256000*256 -> v1 -> y7
  unsigned short* v1  = o0b;
  unsigned short* y7  = o0b;
  unsigned short* Hc  = (unsigned short*)alloc((size_t)32000 * 768 * 2);  // 2-batch chunk

  unsigned short* q1 = (unsigned short*)d_out;                 // bf16 (lower half)
  unsigned short* o1 = (unsigned short*)d_out + 24576000;      // bf16 (upper half)

  // ---- prep ----
  cat3<<<dim3(1), 256, 0, stream>>>(Bf[1], Bf[2], Bf[4], b124);
  cat3<<<dim3(1), 256, 0, stream>>>(Bf[5], Bf[6], Bf[6], b56);  // only first 512 used
  wsplit<<<dim3(96), 256, 0, stream>>>(Wf[0], W0h, W0l, 196608);
  wsplit<<<dim3(96), 256, 0, stream>>>(Wf[3], W3h, W3l, 196608);
  wsplit<<<dim3(32), 256, 0, stream>>>(Wf[7], W7h, W7l, 65536);
  wsplit<<<dim3(96), 256, 0, stream>>>(Wf[1], KVQh, KVQl, 196608);
  wsplit<<<dim3(96), 256, 0, stream>>>(Wf[2], KVQh + 196608, KVQl + 196608, 196608);
  wsplit<<<dim3(96), 256, 0, stream>>>(Wf[4], KVQh + 393216, KVQl + 393216, 196608);
  wsplit<<<dim3(96), 256, 0, stream>>>(Wf[5], KV1h, KV1l, 196608);
  wsplit<<<dim3(96), 256, 0, stream>>>(Wf[6], KV1h + 196608, KV1l + 196608, 196608);

  auto bn1 = [&](float* ps, float* pq, const float* g, const float* z, float2* dst,
                 int gridM, int Cout, float invR) {
    bn_part<<<dim3(64, Cout / 64), 512, 0, stream>>>(ps, pq, pp, gridM, Cout);
    bn_fin<<<dim3(Cout / 64), 64, 0, stream>>>(pp, g, z, dst, Cout, 0, invR);
  };

  // ---- stage 1: q0 (BM32), fused k0|v0|q1 (BM32, PREC4) ----
  gemm7<0, 1, 1, 2, 768, 32><<<dim3(500), 512, 0, stream>>>(
      I, nullptr, nullptr, nullptr, W0h, W0l, Bf[0], nullptr,
      q0, nullptr, psum0, psq0, 256, 256, 0, 1);
  bn1(psum0, psq0, Gf[0], Zf[0], ss + 0 * 768, 500, 256, 1.f / 16000.f);
  gemm7<1, 6, 1, 4, 768, 32><<<dim3(3000), 512, 0, stream>>>(
      nullptr, X, TE, SE, KVQh, KVQl, b124, nullptr,
      kv0, q1, psum0, psq0, 768, 0, 0, 3);
  bn_part<<<dim3(64, 12), 512, 0, stream>>>(psum0, psq0, pp, 3000, 768);
  bn_fin2<<<dim3(8), 64, 0, stream>>>(pp, Gf[1], Zf[1], Gf[2], Zf[2], ssC, 768, 1.f / 96000.f);
  bn_fin<<<dim3(4), 64, 0, stream>>>(pp, Gf[4], Zf[4], ss + 4 * 768, 768, 512, 1.f / 96000.f);

  // ---- attn0 (single launch) -> o0b bf16 ----
  attn_sm<12, 32><<<dim3(500, 16), 512, 0, stream>>>(
      q0, kv0, kv0 + 256, ss + 0 * 768, ssC, ssC + 256, o0b,
      0, (size_t)6000 * 512, (size_t)16000 * 256, 512);

  // ---- m0o stats (one pass, PREC1, BM64) ----
  gemm7<2, 0, 1, 1, 256, 64><<<dim3(4000), 512, 0, stream>>>(
      o0b, nullptr, nullptr, nullptr, W3h, W3l, Bf[3], nullptr,
      nullptr, nullptr, psum0, psq0, 768, 768, 0, 3);
  bn1(psum0, psq0, Gf[3], Zf[3], ss + 3 * 768, 4000, 768, 1.f / 256000.f);

  // ---- pass B: per 2-batch chunk: H (BM64) -> fused k1|v1 (BM32) ----
  for (int cb = 0; cb < 8; ++cb) {
    const size_t oCh = (size_t)cb * 32000 * 256;
    gemm7<2, 2, 0, 2, 256, 64><<<dim3(500), 512, 0, stream>>>(
        o0b + oCh, nullptr, nullptr, nullptr, W3h, W3l, Bf[3], ss + 3 * 768,
        Hc, nullptr, nullptr, nullptr, 768, 768, 0, 3);
    gemm7<2, 5, 0, 3, 768, 32><<<dim3(1000), 512, 0, stream>>>(
        Hc, nullptr, nullptr, nullptr, KV1h, KV1l, b56, nullptr,
        k1 + oCh, v1 + oCh, nullptr, nullptr, 512, 256, 0, 2);
  }

  // ---- m1k / m1v stats from stored raw k1 / v1 ----
  colstats<<<dim3(125), 256, 0, stream>>>(k1, psumK, psqK);
  bn1(psumK, psqK, Gf[5], Zf[5], ss + 5 * 768, 125, 256, 1.f / 256000.f);
  colstats<<<dim3(125), 256, 0, stream>>>(v1, psumK, psqK);
  bn1(psumK, psqK, Gf[6], Zf[6], ss + 6 * 768, 125, 256, 1.f / 256000.f);

  // ---- attn1 (single launch) -> o1 bf16 in d_out upper half ----
  attn_sm<32, 12><<<dim3(500, 16), 192, 0, stream>>>(
      q1, k1, v1, ss + 4 * 768, ss + 5 * 768, ss + 6 * 768, o1,
      (size_t)6000 * 256, (size_t)16000 * 256, (size_t)6000 * 256, 256);

  // ---- m1o -> y7 bf16 (BM64) ----
  gemm7<2, 1, 1, 2, 256, 64><<<dim3(1500), 512, 0, stream>>>(
      o1, nullptr, nullptr, nullptr, W7h, W7l, Bf[7], nullptr,
      y7, nullptr, psum0, psq0, 256, 256, 0, 1);
  bn1(psum0, psq0, Gf[7], Zf[7], ss + 7 * 768, 1500, 256, 1.f / 96000.f);
  bn_relu_addx<<<dim3(12000), 256, 0, stream>>>(y7, ss + 7 * 768, X, (float*)d_out);
}

// Round 19
// 3052.853 us; speedup vs baseline: 1.0003x; 1.0003x over previous
//
#include <hip/hip_runtime.h>
#include <stdint.h>

typedef __bf16 bf16_t;
typedef bf16_t bf16x8 __attribute__((ext_vector_type(8)));
typedef float f32x4 __attribute__((ext_vector_type(4)));

__device__ __forceinline__ float bf2f(unsigned short u) {
  union { unsigned int i; float f; } x; x.i = ((unsigned int)u) << 16; return x.f;
}
__device__ __forceinline__ unsigned short f2bf(float f) {
  union { float f; unsigned int i; } x; x.f = f;
  unsigned int r = x.i + 0x7FFFu + ((x.i >> 16) & 1u);
  return (unsigned short)(r >> 16);
}
__device__ __forceinline__ unsigned pack2(float a, float b) {
  return (unsigned)f2bf(a) | ((unsigned)f2bf(b) << 16);
}

__global__ void cat3(const float* __restrict__ a, const float* __restrict__ b,
                     const float* __restrict__ c, float* __restrict__ dst) {
  int i = threadIdx.x;
  dst[i] = a[i]; dst[256 + i] = b[i]; dst[512 + i] = c[i];
}

__global__ __launch_bounds__(256) void wsplit(
    const float* __restrict__ in, unsigned short* __restrict__ hi,
    unsigned short* __restrict__ lo, int n) {
  int i = (blockIdx.x * 256 + threadIdx.x) * 8;
  if (i >= n) return;
  float4 a = *(const float4*)(in + i);
  float4 b = *(const float4*)(in + i + 4);
  float f[8] = {a.x, a.y, a.z, a.w, b.x, b.y, b.z, b.w};
  unsigned short sh[8], sl[8];
#pragma unroll
  for (int j = 0; j < 8; ++j) {
    sh[j] = f2bf(f[j]);
    sl[j] = f2bf(f[j] - bf2f(sh[j]));
  }
  *(uint4*)(hi + i) = *(uint4*)sh;
  *(uint4*)(lo + i) = *(uint4*)sl;
}

struct f8 { float4 a, b; };

__device__ __forceinline__ f8 ld_c8(const float* __restrict__ X,
                                    const float* __restrict__ TE,
                                    const float* __restrict__ SE,
                                    size_t row, int cc) {
  const float* src = (cc < 256) ? X : ((cc < 512) ? TE : SE);
  const float* p = src + row * 256 + (cc & 255);
  f8 r; r.a = *(const float4*)p; r.b = *(const float4*)(p + 4);
  return r;
}
__device__ __forceinline__ uint4 pack_hi(const float4 a, const float4 b) {
  return make_uint4(pack2(a.x, a.y), pack2(a.z, a.w), pack2(b.x, b.y), pack2(b.z, b.w));
}

// ---------- gemm7: A-panel-resident GEMM, 8 waves, 32 cols/wave, BM rows ----
// A panel staged to LDS once (bf16 hi, XOR-swizzled); column pass = 256 cols
// (wave strips at +0/+128); B in registers, 128-K batches; no K-loop barriers.
// BM=32 halves LDS (K=768: 58 KB -> 2 blocks/CU, 4 waves/SIMD).
// AMODE 0: A fp32. 1: A concat(X,TE,SE) fp32. 2: A bf16 raw.
// PREC 1: hi only. 2: hi+lo. 3: lo for strips >=256 (kv1: v1 cols).
//      4: lo for strips in [256,512) (fused kvq: v0 cols).
// SMODE 0: none, 1: raw bf16, 2: relu(BN) bf16,
//   5: dual raw bf16 (strip<256 -> Cb else Cb2, both stride 256),
//   6: tri raw bf16 (strip<512 -> Cb stride 512; else Cb2 stride 256).
// PART: per-block column partials (width Cout); cstr = C row stride.
template<int AMODE, int SMODE, int PART, int PREC, int K, int BM>
__global__ __launch_bounds__(512) void gemm7(
    const void* __restrict__ Ap, const float* __restrict__ AX,
    const float* __restrict__ ATE, const float* __restrict__ ASE,
    const unsigned short* __restrict__ Wh, const unsigned short* __restrict__ Wl,
    const float* __restrict__ bias, const float2* __restrict__ ssO,
    unsigned short* __restrict__ Cb, unsigned short* __restrict__ Cb2,
    float* __restrict__ psum, float* __restrict__ psq,
    int Cout, int cstr, int pOff, int nx) {
  constexpr int ASH = BM * K;
  constexpr int TOT = ASH + (SMODE != 0 ? BM * 136 : 8);
  constexpr int NC = K / 128;
  constexpr int MR = BM / 16;
  __shared__ unsigned short lds[TOT];
  unsigned short* lA = lds;
  unsigned short* lC = lds + ASH;

  const int tid = threadIdx.x;
  const int lane = tid & 63, wid = tid >> 6;
  const int l15 = lane & 15, l4 = lane >> 4;
  const int brow = blockIdx.x * BM;

  constexpr int CPR = K / 8;
#pragma unroll
  for (int i = 0; i < (BM * CPR) / 512; ++i) {
    int ch = i * 512 + tid;
    int row = ch / CPR, c8 = (ch % CPR) * 8;
    uint4 hv;
    if constexpr (AMODE == 2) {
      hv = *(const uint4*)((const unsigned short*)Ap + (size_t)(brow + row) * K + c8);
    } else if constexpr (AMODE == 0) {
      const float* p = (const float*)Ap + (size_t)(brow + row) * K + c8;
      hv = pack_hi(*(const float4*)p, *(const float4*)(p + 4));
    } else {
      f8 v = ld_c8(AX, ATE, ASE, (size_t)(brow + row), c8);
      hv = pack_hi(v.a, v.b);
    }
    int dst = row * K + (c8 & ~63) + ((c8 & 63) ^ ((row & 7) << 3));
    *(uint4*)(lA + dst) = hv;
  }
  __syncthreads();

  const int axor = (l15 & 7) << 3;
  const int colL = wid * 16 + l15;

  for (int cx = 0; cx < nx; ++cx) {
    const int bcol = cx * 256;
    const int bcs0 = bcol, bcs1 = bcol + 128;
    const bool lo0 = (PREC == 2) || (PREC == 3 && bcs0 >= 256) ||
                     (PREC == 4 && bcs0 >= 256 && bcs0 < 512);
    const bool lo1 = (PREC == 2) || (PREC == 3 && bcs1 >= 256) ||
                     (PREC == 4 && bcs1 >= 256 && bcs1 < 512);
    const unsigned short* wH0 = Wh + (size_t)(bcol + colL) * K + l4 * 8;
    const unsigned short* wH1 = wH0 + (size_t)128 * K;
    const unsigned short* wL0 = nullptr;
    const unsigned short* wL1 = nullptr;
    if constexpr (PREC >= 2) {
      wL0 = Wl + (size_t)(bcol + colL) * K + l4 * 8;
      wL1 = wL0 + (size_t)128 * K;
    }
    f32x4 acc[MR][2] = {};

#pragma unroll
    for (int c = 0; c < NC; ++c) {
      uint4 bh0[4], bh1[4], bl0[4], bl1[4];
#pragma unroll
      for (int ks = 0; ks < 4; ++ks) {
        bh0[ks] = *(const uint4*)(wH0 + c * 128 + ks * 32);
        bh1[ks] = *(const uint4*)(wH1 + c * 128 + ks * 32);
      }
      if constexpr (PREC >= 2) {
        if (lo0) {
#pragma unroll
          for (int ks = 0; ks < 4; ++ks) bl0[ks] = *(const uint4*)(wL0 + c * 128 + ks * 32);
        }
        if (lo1) {
#pragma unroll
          for (int ks = 0; ks < 4; ++ks) bl1[ks] = *(const uint4*)(wL1 + c * 128 + ks * 32);
        }
      }
#pragma unroll
      for (int kk = 0; kk < 4; ++kk) {
        const int kabs = c * 128 + kk * 32;
        const int kt64 = kabs & ~63;
        const int cofs = ((kabs & 32) + l4 * 8) ^ axor;
        bf16x8 af[MR];
#pragma unroll
        for (int m = 0; m < MR; ++m)
          af[m] = *(const bf16x8*)(lA + (m * 16 + l15) * K + kt64 + cofs);
        bf16x8 b0 = *(const bf16x8*)&bh0[kk];
        bf16x8 b1 = *(const bf16x8*)&bh1[kk];
#pragma unroll
        for (int m = 0; m < MR; ++m) {
          acc[m][0] = __builtin_amdgcn_mfma_f32_16x16x32_bf16(af[m], b0, acc[m][0], 0, 0, 0);
          acc[m][1] = __builtin_amdgcn_mfma_f32_16x16x32_bf16(af[m], b1, acc[m][1], 0, 0, 0);
        }
        if constexpr (PREC >= 2) {
          if (lo0) {
            bf16x8 c0 = *(const bf16x8*)&bl0[kk];
#pragma unroll
            for (int m = 0; m < MR; ++m)
              acc[m][0] = __builtin_amdgcn_mfma_f32_16x16x32_bf16(af[m], c0, acc[m][0], 0, 0, 0);
          }
          if (lo1) {
            bf16x8 c1 = *(const bf16x8*)&bl1[kk];
#pragma unroll
            for (int m = 0; m < MR; ++m)
              acc[m][1] = __builtin_amdgcn_mfma_f32_16x16x32_bf16(af[m], c1, acc[m][1], 0, 0, 0);
          }
        }
      }
    }

#pragma unroll
    for (int s = 0; s < 2; ++s) {
      const int bcs = bcol + s * 128;
      const int col = bcs + colL;
      float cs = 0.f, cq = 0.f;
      float bv = bias[col];
      float2 s2 = make_float2(1.f, 0.f);
      if constexpr (SMODE == 2) s2 = ssO[col];
      if constexpr (SMODE != 0) __syncthreads();
#pragma unroll
      for (int m = 0; m < MR; ++m) {
#pragma unroll
        for (int r = 0; r < 4; ++r) {
          float v = acc[m][s][r] + bv;
          if constexpr (PART) { cs += v; cq += v * v; }
          if constexpr (SMODE == 2) v = fmaxf(v * s2.x + s2.y, 0.f);
          if constexpr (SMODE != 0) lC[(m * 16 + l4 * 4 + r) * 136 + colL] = f2bf(v);
        }
      }
      if constexpr (SMODE != 0) {
        __syncthreads();
        const int rw = tid >> 4, c16 = (tid & 15) * 8;
#pragma unroll
        for (int it = 0; it < BM / 32; ++it) {
          int rr = it * 32 + rw;
          uint4 val = *(const uint4*)(lC + rr * 136 + c16);
          if constexpr (SMODE == 5) {
            unsigned short* dst = (bcs < 256) ? Cb : Cb2;
            *(uint4*)(dst + (size_t)(brow + rr) * 256 + (bcs & 255) + c16) = val;
          } else if constexpr (SMODE == 6) {
            if (bcs < 512)
              *(uint4*)(Cb + (size_t)(brow + rr) * 512 + bcs + c16) = val;
            else
              *(uint4*)(Cb2 + (size_t)(brow + rr) * 256 + (bcs - 512) + c16) = val;
          } else {
            *(uint4*)(Cb + (size_t)(brow + rr) * cstr + bcs + c16) = val;
          }
        }
      }
      if constexpr (PART) {
        cs += __shfl_xor(cs, 16); cs += __shfl_xor(cs, 32);
        cq += __shfl_xor(cq, 16); cq += __shfl_xor(cq, 32);
        if (l4 == 0) {
          size_t pidx = (size_t)(pOff + blockIdx.x) * Cout + col;
          psum[pidx] = cs;
          psq[pidx]  = cq;
        }
      }
    }
  }
}

// ---------- column stats of a bf16 [rows][256] tensor; 2048 rows/block ----------
__global__ __launch_bounds__(256) void colstats(
    const unsigned short* __restrict__ A, float* __restrict__ psum,
    float* __restrict__ psq) {
  const int tid = threadIdx.x;
  const int r8 = tid >> 5, co = tid & 31;
  float s[8] = {0,0,0,0,0,0,0,0}, q[8] = {0,0,0,0,0,0,0,0};
  size_t base = (size_t)blockIdx.x * 2048;
  for (int it = 0; it < 256; ++it) {
    size_t row = base + it * 8 + r8;
    uint4 v = *(const uint4*)(A + row * 256 + co * 8);
    const unsigned short* pv = (const unsigned short*)&v;
#pragma unroll
    for (int j = 0; j < 8; ++j) {
      float f = bf2f(pv[j]);
      s[j] += f; q[j] += f * f;
    }
  }
  __shared__ float ls[8][32][8], lq[8][32][8];
#pragma unroll
  for (int j = 0; j < 8; ++j) { ls[r8][co][j] = s[j]; lq[r8][co][j] = q[j]; }
  __syncthreads();
  int co2 = tid >> 3, j2 = tid & 7;
  float S = 0.f, Q = 0.f;
#pragma unroll
  for (int r = 0; r < 8; ++r) { S += ls[r][co2][j2]; Q += lq[r][co2][j2]; }
  psum[(size_t)blockIdx.x * 256 + co2 * 8 + j2] = S;
  psq [(size_t)blockIdx.x * 256 + co2 * 8 + j2] = Q;
}

// ---------- BN stats: row-parallel partial + finalize ----------
__global__ __launch_bounds__(512) void bn_part(
    const float* __restrict__ psum, const float* __restrict__ psq,
    float* __restrict__ pp, int gridM, int Cout) {
  const int lane = threadIdx.x & 63, wv = threadIdx.x >> 6;
  const int c = blockIdx.y * 64 + lane;
  float s = 0.f, q = 0.f;
  for (int r = blockIdx.x + 64 * wv; r < gridM; r += 512) {
    s += psum[(size_t)r * Cout + c];
    q += psq[(size_t)r * Cout + c];
  }
  __shared__ float rs[8][64], rq[8][64];
  rs[wv][lane] = s; rq[wv][lane] = q;
  __syncthreads();
  if (threadIdx.x < 64) {
    float S = 0.f, Q = 0.f;
#pragma unroll
    for (int w2 = 0; w2 < 8; ++w2) { S += rs[w2][threadIdx.x]; Q += rq[w2][threadIdx.x]; }
    pp[(size_t)blockIdx.x * Cout + blockIdx.y * 64 + threadIdx.x] = S;
    pp[(size_t)(64 + blockIdx.x) * Cout + blockIdx.y * 64 + threadIdx.x] = Q;
  }
}
__global__ __launch_bounds__(64) void bn_fin(
    const float* __restrict__ pp, const float* __restrict__ g,
    const float* __restrict__ be, float2* __restrict__ ss,
    int CoutT, int colOff, float invR) {
  int c = blockIdx.x * 64 + threadIdx.x;
  int cp = colOff + c;
  float S = 0.f, Q = 0.f;
  for (int r = 0; r < 64; ++r) {
    S += pp[(size_t)r * CoutT + cp];
    Q += pp[(size_t)(64 + r) * CoutT + cp];
  }
  float mu = S * invR, var = Q * invR - mu * mu;
  float sc = g[c] * rsqrtf(var + 1e-5f);
  ss[c] = make_float2(sc, be[c] - mu * sc);
}
__global__ __launch_bounds__(64) void bn_fin2(
    const float* __restrict__ pp, const float* __restrict__ gA,
    const float* __restrict__ zA, const float* __restrict__ gB,
    const float* __restrict__ zB, float2* __restrict__ ssC,
    int CoutT, float invR) {
  int c = blockIdx.x * 64 + threadIdx.x;
  float S = 0.f, Q = 0.f;
  for (int r = 0; r < 64; ++r) {
    S += pp[(size_t)r * CoutT + c];
    Q += pp[(size_t)(64 + r) * CoutT + c];
  }
  float mu = S * invR, var = Q * invR - mu * mu;
  const float* g = (c < 256) ? gA : gB;
  const float* z = (c < 256) ? zA : zB;
  int ci = c & 255;
  float sc = g[ci] * rsqrtf(var + 1e-5f);
  ssC[c] = make_float2(sc, z[ci] - mu * sc);
}

// ---------- attention: q bf16 (+BN), k/v bf16 (+BN), bf16 out ----------
template<int NK, int NQ>
__global__ void attn_sm(const unsigned short* __restrict__ qy,
                        const unsigned short* __restrict__ ky,
                        const unsigned short* __restrict__ vy,
                        const float2* __restrict__ ssq, const float2* __restrict__ ssk,
                        const float2* __restrict__ ssv, unsigned short* __restrict__ out,
                        size_t qStride, size_t kvStride, size_t oStride, int RS) {
  __shared__ float kl[NK][16][17];
  __shared__ float vl[NK][16][17];
  const int n = blockIdx.x, b = blockIdx.y;
  const int tid = threadIdx.x;
  const unsigned short* kyb = ky + (size_t)b * kvStride;
  const unsigned short* vyb = vy + (size_t)b * kvStride;
  for (int ch = tid; ch < NK * 32; ch += NQ * 16) {
    int t = ch >> 5, c8 = (ch & 31) * 8;
    size_t src = ((size_t)t * 500 + n) * RS + c8;
    uint4 kv = *(const uint4*)(kyb + src);
    uint4 vv = *(const uint4*)(vyb + src);
    const unsigned short* kp = (const unsigned short*)&kv;
    const unsigned short* vp = (const unsigned short*)&vv;
#pragma unroll
    for (int j = 0; j < 8; ++j) {
      int c = c8 + j;
      float2 sk = ssk[c], sv = ssv[c];
      kl[t][c >> 4][c & 15] = fmaxf(bf2f(kp[j]) * sk.x + sk.y, 0.f);
      vl[t][c >> 4][c & 15] = fmaxf(bf2f(vp[j]) * sv.x + sv.y, 0.f);
    }
  }
  __syncthreads();
  const int s = tid >> 4, h = tid & 15;
  unsigned short qraw[16];
  size_t qb = (size_t)b * qStride + ((size_t)s * 500 + n) * 256 + h * 16;
  *(uint4*)qraw = *(const uint4*)(qy + qb);
  *(uint4*)(qraw + 8) = *(const uint4*)(qy + qb + 8);
  float qv[16];
#pragma unroll
  for (int c = 0; c < 16; ++c) {
    float2 sq = ssq[h * 16 + c];
    qv[c] = fmaxf(bf2f(qraw[c]) * sq.x + sq.y, 0.f);
  }
  float lg[NK], mx = -1e30f;
#pragma unroll
  for (int t = 0; t < NK; ++t) {
    float d = 0.f;
#pragma unroll
    for (int c = 0; c < 16; ++c) d += qv[c] * kl[t][h][c];
    lg[t] = d * 0.25f;
    mx = fmaxf(mx, lg[t]);
  }
  float sum = 0.f;
#pragma unroll
  for (int t = 0; t < NK; ++t) { lg[t] = __expf(lg[t] - mx); sum += lg[t]; }
  float inv = 1.f / sum;
  float o[16];
#pragma unroll
  for (int c = 0; c < 16; ++c) o[c] = 0.f;
#pragma unroll
  for (int t = 0; t < NK; ++t) {
    float p = lg[t] * inv;
#pragma unroll
    for (int c = 0; c < 16; ++c) o[c] += p * vl[t][h][c];
  }
  size_t ob = (size_t)b * oStride + ((size_t)s * 500 + n) * 256 + h * 16;
  uint4 w0;
  w0.x = pack2(o[0], o[1]); w0.y = pack2(o[2], o[3]);
  w0.z = pack2(o[4], o[5]); w0.w = pack2(o[6], o[7]);
  *(uint4*)(out + ob) = w0;
  w0.x = pack2(o[8], o[9]); w0.y = pack2(o[10], o[11]);
  w0.z = pack2(o[12], o[13]); w0.w = pack2(o[14], o[15]);
  *(uint4*)(out + ob + 8) = w0;
}

// ---------- final: out = X + relu(BN(y)), y bf16 ----------
__global__ __launch_bounds__(256) void bn_relu_addx(
    const unsigned short* __restrict__ y, const float2* __restrict__ ss,
    const float* __restrict__ X, float* __restrict__ out) {
  int r = blockIdx.x * 8 + (threadIdx.x >> 5);
  int c8 = (threadIdx.x & 31) * 8;
  size_t idx = (size_t)r * 256 + c8;
  uint4 yv4 = *(const uint4*)(y + idx);
  const unsigned short* yv = (const unsigned short*)&yv4;
  float4 x0 = *(const float4*)(X + idx);
  float4 x1 = *(const float4*)(X + idx + 4);
  float ov[8];
#pragma unroll
  for (int j = 0; j < 8; ++j) {
    float2 sc = ss[c8 + j];
    ov[j] = fmaxf(bf2f(yv[j]) * sc.x + sc.y, 0.f);
  }
  *(float4*)(out + idx)     = make_float4(x0.x + ov[0], x0.y + ov[1], x0.z + ov[2], x0.w + ov[3]);
  *(float4*)(out + idx + 4) = make_float4(x1.x + ov[4], x1.y + ov[5], x1.z + ov[6], x1.w + ov[7]);
}

// ---------- launcher ----------
extern "C" void kernel_launch(void* const* d_in, const int* in_sizes, int n_in,
                              void* d_out, int out_size, void* d_ws, size_t ws_size,
                              hipStream_t stream) {
  (void)in_sizes; (void)n_in; (void)out_size; (void)ws_size;
  const float* X  = (const float*)d_in[0];
  const float* TE = (const float*)d_in[1];
  const float* SE = (const float*)d_in[2];
  const float* I  = (const float*)d_in[3];
  const float *Wf[8], *Bf[8], *Gf[8], *Zf[8];
  for (int l = 0; l < 8; ++l) {
    Wf[l] = (const float*)d_in[4 + l * 4 + 0];
    Bf[l] = (const float*)d_in[4 + l * 4 + 1];
    Gf[l] = (const float*)d_in[4 + l * 4 + 2];
    Zf[l] = (const float*)d_in[4 + l * 4 + 3];
  }

  char* w = (char*)d_ws;
  size_t off = 0;
  auto alloc = [&](size_t bytes) -> void* {
    void* p = w + off;
    off += (bytes + 255) & ~(size_t)255;
    return p;
  };

  // ---- workspace (~342 MB; ws >= 345 MB proven) ----
  float* psum0 = (float*)alloc((size_t)4000 * 768 * 4);
  float* psq0  = (float*)alloc((size_t)4000 * 768 * 4);
  float* psumK = (float*)alloc((size_t)125 * 256 * 4);
  float* psqK  = (float*)alloc((size_t)125 * 256 * 4);
  float* pp    = (float*)alloc((size_t)128 * 768 * 4);
  float2* ss   = (float2*)alloc((size_t)(8 * 768 + 512) * sizeof(float2));
  float2* ssC  = ss + 8 * 768;
  unsigned short *W0h, *W0l, *W3h, *W3l, *W7h, *W7l;
  unsigned short *KVQh, *KVQl, *KV1h, *KV1l;
  W0h = (unsigned short*)alloc(196608 * 2); W0l = (unsigned short*)alloc(196608 * 2);
  W3h = (unsigned short*)alloc(196608 * 2); W3l = (unsigned short*)alloc(196608 * 2);
  W7h = (unsigned short*)alloc(65536 * 2);  W7l = (unsigned short*)alloc(65536 * 2);
  KVQh = (unsigned short*)alloc(589824 * 2); KVQl = (unsigned short*)alloc(589824 * 2);
  KV1h = (unsigned short*)alloc(393216 * 2); KV1l = (unsigned short*)alloc(393216 * 2);
  float* b124 = (float*)alloc(768 * 4);
  float* b56  = (float*)alloc(512 * 4);
  // region R: q0 | kv0 | pad  == exactly k1 [256000][256] bf16 later
  char* R = (char*)alloc(131072000);
  unsigned short* q0  = (unsigned short*)R;                    // 16000*256
  unsigned short* kv0 = (unsigned short*)(R + 8192000);        // 96000*512
  unsigned short* k1  = (unsigned short*)R;                    // 256000*256
  unsigned short* o0b = (unsigned short*)alloc(131072000);     // 256000*256 -> v1 -> y7
  unsigned short* v1  = o0b;
  unsigned short* y7  = o0b;
  unsigned short* Hc  = (unsigned short*)alloc((size_t)32000 * 768 * 2);  // 2-batch chunk

  unsigned short* q1 = (unsigned short*)d_out;                 // bf16 (lower half)
  unsigned short* o1 = (unsigned short*)d_out + 24576000;      // bf16 (upper half)

  // ---- prep ----
  cat3<<<dim3(1), 256, 0, stream>>>(Bf[1], Bf[2], Bf[4], b124);
  cat3<<<dim3(1), 256, 0, stream>>>(Bf[5], Bf[6], Bf[6], b56);  // only first 512 used
  wsplit<<<dim3(96), 256, 0, stream>>>(Wf[0], W0h, W0l, 196608);
  wsplit<<<dim3(96), 256, 0, stream>>>(Wf[3], W3h, W3l, 196608);
  wsplit<<<dim3(32), 256, 0, stream>>>(Wf[7], W7h, W7l, 65536);
  wsplit<<<dim3(96), 256, 0, stream>>>(Wf[1], KVQh, KVQl, 196608);
  wsplit<<<dim3(96), 256, 0, stream>>>(Wf[2], KVQh + 196608, KVQl + 196608, 196608);
  wsplit<<<dim3(96), 256, 0, stream>>>(Wf[4], KVQh + 393216, KVQl + 393216, 196608);
  wsplit<<<dim3(96), 256, 0, stream>>>(Wf[5], KV1h, KV1l, 196608);
  wsplit<<<dim3(96), 256, 0, stream>>>(Wf[6], KV1h + 196608, KV1l + 196608, 196608);

  auto bn1 = [&](float* ps, float* pq, const float* g, const float* z, float2* dst,
                 int gridM, int Cout, float invR) {
    bn_part<<<dim3(64, Cout / 64), 512, 0, stream>>>(ps, pq, pp, gridM, Cout);
    bn_fin<<<dim3(Cout / 64), 64, 0, stream>>>(pp, g, z, dst, Cout, 0, invR);
  };

  // ---- stage 1: q0 (BM32), fused k0|v0|q1 (BM32, PREC4) ----
  gemm7<0, 1, 1, 2, 768, 32><<<dim3(500), 512, 0, stream>>>(
      I, nullptr, nullptr, nullptr, W0h, W0l, Bf[0], nullptr,
      q0, nullptr, psum0, psq0, 256, 256, 0, 1);
  bn1(psum0, psq0, Gf[0], Zf[0], ss + 0 * 768, 500, 256, 1.f / 16000.f);
  gemm7<1, 6, 1, 4, 768, 32><<<dim3(3000), 512, 0, stream>>>(
      nullptr, X, TE, SE, KVQh, KVQl, b124, nullptr,
      kv0, q1, psum0, psq0, 768, 0, 0, 3);
  bn_part<<<dim3(64, 12), 512, 0, stream>>>(psum0, psq0, pp, 3000, 768);
  bn_fin2<<<dim3(8), 64, 0, stream>>>(pp, Gf[1], Zf[1], Gf[2], Zf[2], ssC, 768, 1.f / 96000.f);
  bn_fin<<<dim3(4), 64, 0, stream>>>(pp, Gf[4], Zf[4], ss + 4 * 768, 768, 512, 1.f / 96000.f);

  // ---- attn0 (single launch) -> o0b bf16 ----
  attn_sm<12, 32><<<dim3(500, 16), 512, 0, stream>>>(
      q0, kv0, kv0 + 256, ss + 0 * 768, ssC, ssC + 256, o0b,
      0, (size_t)6000 * 512, (size_t)16000 * 256, 512);

  // ---- m0o stats (one pass, PREC1, BM64) ----
  gemm7<2, 0, 1, 1, 256, 64><<<dim3(4000), 512, 0, stream>>>(
      o0b, nullptr, nullptr, nullptr, W3h, W3l, Bf[3], nullptr,
      nullptr, nullptr, psum0, psq0, 768, 768, 0, 3);
  bn1(psum0, psq0, Gf[3], Zf[3], ss + 3 * 768, 4000, 768, 1.f / 256000.f);

  // ---- pass B: per 2-batch chunk: H (BM64) -> fused k1|v1 (BM32) ----
  for (int cb = 0; cb < 8; ++cb) {
    const size_t oCh = (size_t)cb * 32000 * 256;
    gemm7<2, 2, 0, 2, 256, 64><<<dim3(500), 512, 0, stream>>>(
        o0b + oCh, nullptr, nullptr, nullptr, W3h, W3l, Bf[3], ss + 3 * 768,
        Hc, nullptr, nullptr, nullptr, 768, 768, 0, 3);
    gemm7<2, 5, 0, 3, 768, 32><<<dim3(1000), 512, 0, stream>>>(
        Hc, nullptr, nullptr, nullptr, KV1h, KV1l, b56, nullptr,
        k1 + oCh, v1 + oCh, nullptr, nullptr, 512, 256, 0, 2);
  }

  // ---- m1k / m1v stats from stored raw k1 / v1 ----
  colstats<<<dim3(125), 256, 0, stream>>>(k1, psumK, psqK);
  bn1(psumK, psqK, Gf[5], Zf[5], ss + 5 * 768, 125, 256, 1.f / 256000.f);
  colstats<<<dim3(125), 256, 0, stream>>>(v1, psumK, psqK);
  bn1(psumK, psqK, Gf[6], Zf[6], ss + 6 * 768, 125, 256, 1.f / 256000.f);

  // ---- attn1 (single launch) -> o1 bf16 in d_out upper half ----
  attn_sm<32, 12><<<dim3(500, 16), 192, 0, stream>>>(
      q1, k1, v1, ss + 4 * 768, ss + 5 * 768, ss + 6 * 768, o1,
      (size_t)6000 * 256, (size_t)16000 * 256, (size_t)6000 * 256, 256);

  // ---- m1o -> y7 bf16 (BM64) ----
  gemm7<2, 1, 1, 2, 256, 64><<<dim3(1500), 512, 0, stream>>>(
      o1, nullptr, nullptr, nullptr, W7h, W7l, Bf[7], nullptr,
      y7, nullptr, psum0, psq0, 256, 256, 0, 1);
  bn1(psum0, psq0, Gf[7], Zf[7], ss + 7 * 768, 1500, 256, 1.f / 96000.f);
  bn_relu_addx<<<dim3(12000), 256, 0, stream>>>(y7, ss + 7 * 768, X, (float*)d_out);
}

// Round 20
// 2397.323 us; speedup vs baseline: 1.2739x; 1.2734x over previous
//
#include <hip/hip_runtime.h>
#include <stdint.h>

typedef __bf16 bf16_t;
typedef bf16_t bf16x8 __attribute__((ext_vector_type(8)));
typedef float f32x4 __attribute__((ext_vector_type(4)));

__device__ __forceinline__ float bf2f(unsigned short u) {
  union { unsigned int i; float f; } x; x.i = ((unsigned int)u) << 16; return x.f;
}
__device__ __forceinline__ unsigned short f2bf(float f) {
  union { float f; unsigned int i; } x; x.f = f;
  unsigned int r = x.i + 0x7FFFu + ((x.i >> 16) & 1u);
  return (unsigned short)(r >> 16);
}
__device__ __forceinline__ unsigned pack2(float a, float b) {
  return (unsigned)f2bf(a) | ((unsigned)f2bf(b) << 16);
}

__global__ void cat3(const float* __restrict__ a, const float* __restrict__ b,
                     const float* __restrict__ c, float* __restrict__ dst) {
  int i = threadIdx.x;
  dst[i] = a[i]; dst[256 + i] = b[i]; dst[512 + i] = c[i];
}

__global__ __launch_bounds__(256) void wsplit(
    const float* __restrict__ in, unsigned short* __restrict__ hi,
    unsigned short* __restrict__ lo, int n) {
  int i = (blockIdx.x * 256 + threadIdx.x) * 8;
  if (i >= n) return;
  float4 a = *(const float4*)(in + i);
  float4 b = *(const float4*)(in + i + 4);
  float f[8] = {a.x, a.y, a.z, a.w, b.x, b.y, b.z, b.w};
  unsigned short sh[8], sl[8];
#pragma unroll
  for (int j = 0; j < 8; ++j) {
    sh[j] = f2bf(f[j]);
    sl[j] = f2bf(f[j] - bf2f(sh[j]));
  }
  *(uint4*)(hi + i) = *(uint4*)sh;
  *(uint4*)(lo + i) = *(uint4*)sl;
}

struct f8 { float4 a, b; };

__device__ __forceinline__ f8 ld_c8(const float* __restrict__ X,
                                    const float* __restrict__ TE,
                                    const float* __restrict__ SE,
                                    size_t row, int cc) {
  const float* src = (cc < 256) ? X : ((cc < 512) ? TE : SE);
  const float* p = src + row * 256 + (cc & 255);
  f8 r; r.a = *(const float4*)p; r.b = *(const float4*)(p + 4);
  return r;
}
__device__ __forceinline__ uint4 pack_hi(const float4 a, const float4 b) {
  return make_uint4(pack2(a.x, a.y), pack2(a.z, a.w), pack2(b.x, b.y), pack2(b.z, b.w));
}

// ---------- gemm7: A-panel-resident GEMM, 8 waves, 32 cols/wave, BM rows ----
// A panel staged to LDS once (bf16 hi, XOR-swizzled); column pass = 256 cols
// (wave strips at +0/+128); B in registers, 128-K batches; no K-loop barriers.
// AMODE 0: A fp32. 1: A concat(X,TE,SE) fp32. 2: A bf16 raw.
// PREC 1: hi only. 2: hi+lo. 3: lo for strips >=256 (kv1: v1 cols).
//      4: lo for strips in [256,512) (fused kvq: v0 cols).
// SMODE 0: none, 1: raw bf16, 2: relu(BN) bf16,
//   5: dual raw bf16 (strip<256 -> Cb else Cb2, both stride 256),
//   6: tri raw bf16 (strip<512 -> Cb stride 512; else Cb2 stride 256).
// PART: per-block column partials (width Cout); cstr = C row stride.
template<int AMODE, int SMODE, int PART, int PREC, int K, int BM>
__global__ __launch_bounds__(512) void gemm7(
    const void* __restrict__ Ap, const float* __restrict__ AX,
    const float* __restrict__ ATE, const float* __restrict__ ASE,
    const unsigned short* __restrict__ Wh, const unsigned short* __restrict__ Wl,
    const float* __restrict__ bias, const float2* __restrict__ ssO,
    unsigned short* __restrict__ Cb, unsigned short* __restrict__ Cb2,
    float* __restrict__ psum, float* __restrict__ psq,
    int Cout, int cstr, int pOff, int nx) {
  constexpr int ASH = BM * K;
  constexpr int TOT = ASH + (SMODE != 0 ? BM * 136 : 8);
  constexpr int NC = K / 128;
  constexpr int MR = BM / 16;
  __shared__ unsigned short lds[TOT];
  unsigned short* lA = lds;
  unsigned short* lC = lds + ASH;

  const int tid = threadIdx.x;
  const int lane = tid & 63, wid = tid >> 6;
  const int l15 = lane & 15, l4 = lane >> 4;
  const int brow = blockIdx.x * BM;

  constexpr int CPR = K / 8;
#pragma unroll
  for (int i = 0; i < (BM * CPR) / 512; ++i) {
    int ch = i * 512 + tid;
    int row = ch / CPR, c8 = (ch % CPR) * 8;
    uint4 hv;
    if constexpr (AMODE == 2) {
      hv = *(const uint4*)((const unsigned short*)Ap + (size_t)(brow + row) * K + c8);
    } else if constexpr (AMODE == 0) {
      const float* p = (const float*)Ap + (size_t)(brow + row) * K + c8;
      hv = pack_hi(*(const float4*)p, *(const float4*)(p + 4));
    } else {
      f8 v = ld_c8(AX, ATE, ASE, (size_t)(brow + row), c8);
      hv = pack_hi(v.a, v.b);
    }
    int dst = row * K + (c8 & ~63) + ((c8 & 63) ^ ((row & 7) << 3));
    *(uint4*)(lA + dst) = hv;
  }
  __syncthreads();

  const int axor = (l15 & 7) << 3;
  const int colL = wid * 16 + l15;

  for (int cx = 0; cx < nx; ++cx) {
    const int bcol = cx * 256;
    const int bcs0 = bcol, bcs1 = bcol + 128;
    const bool lo0 = (PREC == 2) || (PREC == 3 && bcs0 >= 256) ||
                     (PREC == 4 && bcs0 >= 256 && bcs0 < 512);
    const bool lo1 = (PREC == 2) || (PREC == 3 && bcs1 >= 256) ||
                     (PREC == 4 && bcs1 >= 256 && bcs1 < 512);
    const unsigned short* wH0 = Wh + (size_t)(bcol + colL) * K + l4 * 8;
    const unsigned short* wH1 = wH0 + (size_t)128 * K;
    const unsigned short* wL0 = nullptr;
    const unsigned short* wL1 = nullptr;
    if constexpr (PREC >= 2) {
      wL0 = Wl + (size_t)(bcol + colL) * K + l4 * 8;
      wL1 = wL0 + (size_t)128 * K;
    }
    f32x4 acc[MR][2] = {};

#pragma unroll
    for (int c = 0; c < NC; ++c) {
      uint4 bh0[4], bh1[4], bl0[4], bl1[4];
#pragma unroll
      for (int ks = 0; ks < 4; ++ks) {
        bh0[ks] = *(const uint4*)(wH0 + c * 128 + ks * 32);
        bh1[ks] = *(const uint4*)(wH1 + c * 128 + ks * 32);
      }
      if constexpr (PREC >= 2) {
        if (lo0) {
#pragma unroll
          for (int ks = 0; ks < 4; ++ks) bl0[ks] = *(const uint4*)(wL0 + c * 128 + ks * 32);
        }
        if (lo1) {
#pragma unroll
          for (int ks = 0; ks < 4; ++ks) bl1[ks] = *(const uint4*)(wL1 + c * 128 + ks * 32);
        }
      }
#pragma unroll
      for (int kk = 0; kk < 4; ++kk) {
        const int kabs = c * 128 + kk * 32;
        const int kt64 = kabs & ~63;
        const int cofs = ((kabs & 32) + l4 * 8) ^ axor;
        bf16x8 af[MR];
#pragma unroll
        for (int m = 0; m < MR; ++m)
          af[m] = *(const bf16x8*)(lA + (m * 16 + l15) * K + kt64 + cofs);
        bf16x8 b0 = *(const bf16x8*)&bh0[kk];
        bf16x8 b1 = *(const bf16x8*)&bh1[kk];
#pragma unroll
        for (int m = 0; m < MR; ++m) {
          acc[m][0] = __builtin_amdgcn_mfma_f32_16x16x32_bf16(af[m], b0, acc[m][0], 0, 0, 0);
          acc[m][1] = __builtin_amdgcn_mfma_f32_16x16x32_bf16(af[m], b1, acc[m][1], 0, 0, 0);
        }
        if constexpr (PREC >= 2) {
          if (lo0) {
            bf16x8 c0 = *(const bf16x8*)&bl0[kk];
#pragma unroll
            for (int m = 0; m < MR; ++m)
              acc[m][0] = __builtin_amdgcn_mfma_f32_16x16x32_bf16(af[m], c0, acc[m][0], 0, 0, 0);
          }
          if (lo1) {
            bf16x8 c1 = *(const bf16x8*)&bl1[kk];
#pragma unroll
            for (int m = 0; m < MR; ++m)
              acc[m][1] = __builtin_amdgcn_mfma_f32_16x16x32_bf16(af[m], c1, acc[m][1], 0, 0, 0);
          }
        }
      }
    }

#pragma unroll
    for (int s = 0; s < 2; ++s) {
      const int bcs = bcol + s * 128;
      const int col = bcs + colL;
      float cs = 0.f, cq = 0.f;
      float bv = bias[col];
      float2 s2 = make_float2(1.f, 0.f);
      if constexpr (SMODE == 2) s2 = ssO[col];
      if constexpr (SMODE != 0) __syncthreads();
#pragma unroll
      for (int m = 0; m < MR; ++m) {
#pragma unroll
        for (int r = 0; r < 4; ++r) {
          float v = acc[m][s][r] + bv;
          if constexpr (PART) { cs += v; cq += v * v; }
          if constexpr (SMODE == 2) v = fmaxf(v * s2.x + s2.y, 0.f);
          if constexpr (SMODE != 0) lC[(m * 16 + l4 * 4 + r) * 136 + colL] = f2bf(v);
        }
      }
      if constexpr (SMODE != 0) {
        __syncthreads();
        const int rw = tid >> 4, c16 = (tid & 15) * 8;
#pragma unroll
        for (int it = 0; it < BM / 32; ++it) {
          int rr = it * 32 + rw;
          uint4 val = *(const uint4*)(lC + rr * 136 + c16);
          if constexpr (SMODE == 5) {
            unsigned short* dst = (bcs < 256) ? Cb : Cb2;
            *(uint4*)(dst + (size_t)(brow + rr) * 256 + (bcs & 255) + c16) = val;
          } else if constexpr (SMODE == 6) {
            if (bcs < 512)
              *(uint4*)(Cb + (size_t)(brow + rr) * 512 + bcs + c16) = val;
            else
              *(uint4*)(Cb2 + (size_t)(brow + rr) * 256 + (bcs - 512) + c16) = val;
          } else {
            *(uint4*)(Cb + (size_t)(brow + rr) * cstr + bcs + c16) = val;
          }
        }
      }
      if constexpr (PART) {
        cs += __shfl_xor(cs, 16); cs += __shfl_xor(cs, 32);
        cq += __shfl_xor(cq, 16); cq += __shfl_xor(cq, 32);
        if (l4 == 0) {
          size_t pidx = (size_t)(pOff + blockIdx.x) * Cout + col;
          psum[pidx] = cs;
          psq[pidx]  = cq;
        }
      }
    }
  }
}

// ---------- column stats of a bf16 [rows][256] tensor; 2048 rows/block ----------
__global__ __launch_bounds__(256) void colstats(
    const unsigned short* __restrict__ A, float* __restrict__ psum,
    float* __restrict__ psq) {
  const int tid = threadIdx.x;
  const int r8 = tid >> 5, co = tid & 31;
  float s[8] = {0,0,0,0,0,0,0,0}, q[8] = {0,0,0,0,0,0,0,0};
  size_t base = (size_t)blockIdx.x * 2048;
  for (int it = 0; it < 256; ++it) {
    size_t row = base + it * 8 + r8;
    uint4 v = *(const uint4*)(A + row * 256 + co * 8);
    const unsigned short* pv = (const unsigned short*)&v;
#pragma unroll
    for (int j = 0; j < 8; ++j) {
      float f = bf2f(pv[j]);
      s[j] += f; q[j] += f * f;
    }
  }
  __shared__ float ls[8][32][8], lq[8][32][8];
#pragma unroll
  for (int j = 0; j < 8; ++j) { ls[r8][co][j] = s[j]; lq[r8][co][j] = q[j]; }
  __syncthreads();
  int co2 = tid >> 3, j2 = tid & 7;
  float S = 0.f, Q = 0.f;
#pragma unroll
  for (int r = 0; r < 8; ++r) { S += ls[r][co2][j2]; Q += lq[r][co2][j2]; }
  psum[(size_t)blockIdx.x * 256 + co2 * 8 + j2] = S;
  psq [(size_t)blockIdx.x * 256 + co2 * 8 + j2] = Q;
}

// ---------- BN stats: row-parallel partial + finalize ----------
__global__ __launch_bounds__(512) void bn_part(
    const float* __restrict__ psum, const float* __restrict__ psq,
    float* __restrict__ pp, int gridM, int Cout) {
  const int lane = threadIdx.x & 63, wv = threadIdx.x >> 6;
  const int c = blockIdx.y * 64 + lane;
  float s = 0.f, q = 0.f;
  for (int r = blockIdx.x + 64 * wv; r < gridM; r += 512) {
    s += psum[(size_t)r * Cout + c];
    q += psq[(size_t)r * Cout + c];
  }
  __shared__ float rs[8][64], rq[8][64];
  rs[wv][lane] = s; rq[wv][lane] = q;
  __syncthreads();
  if (threadIdx.x < 64) {
    float S = 0.f, Q = 0.f;
#pragma unroll
    for (int w2 = 0; w2 < 8; ++w2) { S += rs[w2][threadIdx.x]; Q += rq[w2][threadIdx.x]; }
    pp[(size_t)blockIdx.x * Cout + blockIdx.y * 64 + threadIdx.x] = S;
    pp[(size_t)(64 + blockIdx.x) * Cout + blockIdx.y * 64 + threadIdx.x] = Q;
  }
}
__global__ __launch_bounds__(64) void bn_fin(
    const float* __restrict__ pp, const float* __restrict__ g,
    const float* __restrict__ be, float2* __restrict__ ss,
    int CoutT, int colOff, float invR) {
  int c = blockIdx.x * 64 + threadIdx.x;
  int cp = colOff + c;
  float S = 0.f, Q = 0.f;
  for (int r = 0; r < 64; ++r) {
    S += pp[(size_t)r * CoutT + cp];
    Q += pp[(size_t)(64 + r) * CoutT + cp];
  }
  float mu = S * invR, var = Q * invR - mu * mu;
  float sc = g[c] * rsqrtf(var + 1e-5f);
  ss[c] = make_float2(sc, be[c] - mu * sc);
}
__global__ __launch_bounds__(64) void bn_fin2(
    const float* __restrict__ pp, const float* __restrict__ gA,
    const float* __restrict__ zA, const float* __restrict__ gB,
    const float* __restrict__ zB, float2* __restrict__ ssC,
    int CoutT, float invR) {
  int c = blockIdx.x * 64 + threadIdx.x;
  float S = 0.f, Q = 0.f;
  for (int r = 0; r < 64; ++r) {
    S += pp[(size_t)r * CoutT + c];
    Q += pp[(size_t)(64 + r) * CoutT + c];
  }
  float mu = S * invR, var = Q * invR - mu * mu;
  const float* g = (c < 256) ? gA : gB;
  const float* z = (c < 256) ? zA : zB;
  int ci = c & 255;
  float sc = g[ci] * rsqrtf(var + 1e-5f);
  ssC[c] = make_float2(sc, z[ci] - mu * sc);
}

// ---------- attention: q bf16 (+BN), k/v bf16 (+BN), bf16 out ----------
template<int NK, int NQ>
__global__ void attn_sm(const unsigned short* __restrict__ qy,
                        const unsigned short* __restrict__ ky,
                        const unsigned short* __restrict__ vy,
                        const float2* __restrict__ ssq, const float2* __restrict__ ssk,
                        const float2* __restrict__ ssv, unsigned short* __restrict__ out,
                        size_t qStride, size_t kvStride, size_t oStride, int RS) {
  __shared__ float kl[NK][16][17];
  __shared__ float vl[NK][16][17];
  const int n = blockIdx.x, b = blockIdx.y;
  const int tid = threadIdx.x;
  const unsigned short* kyb = ky + (size_t)b * kvStride;
  const unsigned short* vyb = vy + (size_t)b * kvStride;
  for (int ch = tid; ch < NK * 32; ch += NQ * 16) {
    int t = ch >> 5, c8 = (ch & 31) * 8;
    size_t src = ((size_t)t * 500 + n) * RS + c8;
    uint4 kv = *(const uint4*)(kyb + src);
    uint4 vv = *(const uint4*)(vyb + src);
    const unsigned short* kp = (const unsigned short*)&kv;
    const unsigned short* vp = (const unsigned short*)&vv;
#pragma unroll
    for (int j = 0; j < 8; ++j) {
      int c = c8 + j;
      float2 sk = ssk[c], sv = ssv[c];
      kl[t][c >> 4][c & 15] = fmaxf(bf2f(kp[j]) * sk.x + sk.y, 0.f);
      vl[t][c >> 4][c & 15] = fmaxf(bf2f(vp[j]) * sv.x + sv.y, 0.f);
    }
  }
  __syncthreads();
  const int s = tid >> 4, h = tid & 15;
  unsigned short qraw[16];
  size_t qb = (size_t)b * qStride + ((size_t)s * 500 + n) * 256 + h * 16;
  *(uint4*)qraw = *(const uint4*)(qy + qb);
  *(uint4*)(qraw + 8) = *(const uint4*)(qy + qb + 8);
  float qv[16];
#pragma unroll
  for (int c = 0; c < 16; ++c) {
    float2 sq = ssq[h * 16 + c];
    qv[c] = fmaxf(bf2f(qraw[c]) * sq.x + sq.y, 0.f);
  }
  float lg[NK], mx = -1e30f;
#pragma unroll
  for (int t = 0; t < NK; ++t) {
    float d = 0.f;
#pragma unroll
    for (int c = 0; c < 16; ++c) d += qv[c] * kl[t][h][c];
    lg[t] = d * 0.25f;
    mx = fmaxf(mx, lg[t]);
  }
  float sum = 0.f;
#pragma unroll
  for (int t = 0; t < NK; ++t) { lg[t] = __expf(lg[t] - mx); sum += lg[t]; }
  float inv = 1.f / sum;
  float o[16];
#pragma unroll
  for (int c = 0; c < 16; ++c) o[c] = 0.f;
#pragma unroll
  for (int t = 0; t < NK; ++t) {
    float p = lg[t] * inv;
#pragma unroll
    for (int c = 0; c < 16; ++c) o[c] += p * vl[t][h][c];
  }
  size_t ob = (size_t)b * oStride + ((size_t)s * 500 + n) * 256 + h * 16;
  uint4 w0;
  w0.x = pack2(o[0], o[1]); w0.y = pack2(o[2], o[3]);
  w0.z = pack2(o[4], o[5]); w0.w = pack2(o[6], o[7]);
  *(uint4*)(out + ob) = w0;
  w0.x = pack2(o[8], o[9]); w0.y = pack2(o[10], o[11]);
  w0.z = pack2(o[12], o[13]); w0.w = pack2(o[14], o[15]);
  *(uint4*)(out + ob + 8) = w0;
}

// ---------- final: out = X + relu(BN(y)), y bf16 ----------
__global__ __launch_bounds__(256) void bn_relu_addx(
    const unsigned short* __restrict__ y, const float2* __restrict__ ss,
    const float* __restrict__ X, float* __restrict__ out) {
  int r = blockIdx.x * 8 + (threadIdx.x >> 5);
  int c8 = (threadIdx.x & 31) * 8;
  size_t idx = (size_t)r * 256 + c8;
  uint4 yv4 = *(const uint4*)(y + idx);
  const unsigned short* yv = (const unsigned short*)&yv4;
  float4 x0 = *(const float4*)(X + idx);
  float4 x1 = *(const float4*)(X + idx + 4);
  float ov[8];
#pragma unroll
  for (int j = 0; j < 8; ++j) {
    float2 sc = ss[c8 + j];
    ov[j] = fmaxf(bf2f(yv[j]) * sc.x + sc.y, 0.f);
  }
  *(float4*)(out + idx)     = make_float4(x0.x + ov[0], x0.y + ov[1], x0.z + ov[2], x0.w + ov[3]);
  *(float4*)(out + idx + 4) = make_float4(x1.x + ov[4], x1.y + ov[5], x1.z + ov[6], x1.w + ov[7]);
}

// ---------- launcher ----------
extern "C" void kernel_launch(void* const* d_in, const int* in_sizes, int n_in,
                              void* d_out, int out_size, void* d_ws, size_t ws_size,
                              hipStream_t stream) {
  (void)in_sizes; (void)n_in; (void)out_size; (void)ws_size;
  const float* X  = (const float*)d_in[0];
  const float* TE = (const float*)d_in[1];
  const float* SE = (const float*)d_in[2];
  const float* I  = (const float*)d_in[3];
  const float *Wf[8], *Bf[8], *Gf[8], *Zf[8];
  for (int l = 0; l < 8; ++l) {
    Wf[l] = (const float*)d_in[4 + l * 4 + 0];
    Bf[l] = (const float*)d_in[4 + l * 4 + 1];
    Gf[l] = (const float*)d_in[4 + l * 4 + 2];
    Zf[l] = (const float*)d_in[4 + l * 4 + 3];
  }

  char* w = (char*)d_ws;
  size_t off = 0;
  auto alloc = [&](size_t bytes) -> void* {
    void* p = w + off;
    off += (bytes + 255) & ~(size_t)255;
    return p;
  };

  // ---- workspace (~342 MB; ws >= 345 MB proven) ----
  float* psum0 = (float*)alloc((size_t)4000 * 768 * 4);
  float* psq0  = (float*)alloc((size_t)4000 * 768 * 4);
  float* psumK = (float*)alloc((size_t)125 * 256 * 4);
  float* psqK  = (float*)alloc((size_t)125 * 256 * 4);
  float* pp    = (float*)alloc((size_t)128 * 768 * 4);
  float2* ss   = (float2*)alloc((size_t)(8 * 768 + 512) * sizeof(float2));
  float2* ssC  = ss + 8 * 768;
  unsigned short *W0h, *W0l, *W3h, *W3l, *W7h, *W7l;
  unsigned short *KVQh, *KVQl, *KV1h, *KV1l;
  W0h = (unsigned short*)alloc(196608 * 2); W0l = (unsigned short*)alloc(196608 * 2);
  W3h = (unsigned short*)alloc(196608 * 2); W3l = (unsigned short*)alloc(196608 * 2);
  W7h = (unsigned short*)alloc(65536 * 2);  W7l = (unsigned short*)alloc(65536 * 2);
  KVQh = (unsigned short*)alloc(589824 * 2); KVQl = (unsigned short*)alloc(589824 * 2);
  KV1h = (unsigned short*)alloc(393216 * 2); KV1l = (unsigned short*)alloc(393216 * 2);
  float* b124 = (float*)alloc(768 * 4);
  float* b56  = (float*)alloc(512 * 4);
  // region R: q0 | kv0 | pad  == exactly k1 [256000][256] bf16 later
  char* R = (char*)alloc(131072000);
  unsigned short* q0  = (unsigned short*)R;                    // 16000*256
  unsigned short* kv0 = (unsigned short*)(R + 8192000);        // 96000*512
  unsigned short* k1  = (unsigned short*)R;                    // 256000*256
  unsigned short* o0b = (unsigned short*)alloc(131072000);     // 256000*256 -> v1 -> y7
  unsigned short* v1  = o0b;
  unsigned short* y7  = o0b;
  unsigned short* Hc  = (unsigned short*)alloc((size_t)32000 * 768 * 2);  // 2-batch chunk

  unsigned short* q1 = (unsigned short*)d_out;                 // bf16 (lower half)
  unsigned short* o1 = (unsigned short*)d_out + 24576000;      // bf16 (upper half)

  // ---- prep ----
  cat3<<<dim3(1), 256, 0, stream>>>(Bf[1], Bf[2], Bf[4], b124);
  cat3<<<dim3(1), 256, 0, stream>>>(Bf[5], Bf[6], Bf[6], b56);  // only first 512 used
  wsplit<<<dim3(96), 256, 0, stream>>>(Wf[0], W0h, W0l, 196608);
  wsplit<<<dim3(96), 256, 0, stream>>>(Wf[3], W3h, W3l, 196608);
  wsplit<<<dim3(32), 256, 0, stream>>>(Wf[7], W7h, W7l, 65536);
  wsplit<<<dim3(96), 256, 0, stream>>>(Wf[1], KVQh, KVQl, 196608);
  wsplit<<<dim3(96), 256, 0, stream>>>(Wf[2], KVQh + 196608, KVQl + 196608, 196608);
  wsplit<<<dim3(96), 256, 0, stream>>>(Wf[4], KVQh + 393216, KVQl + 393216, 196608);
  wsplit<<<dim3(96), 256, 0, stream>>>(Wf[5], KV1h, KV1l, 196608);
  wsplit<<<dim3(96), 256, 0, stream>>>(Wf[6], KV1h + 196608, KV1l + 196608, 196608);

  auto bn1 = [&](float* ps, float* pq, const float* g, const float* z, float2* dst,
                 int gridM, int Cout, float invR) {
    bn_part<<<dim3(64, Cout / 64), 512, 0, stream>>>(ps, pq, pp, gridM, Cout);
    bn_fin<<<dim3(Cout / 64), 64, 0, stream>>>(pp, g, z, dst, Cout, 0, invR);
  };

  // ---- stage 1: q0, fused k0|v0|q1 (BM64, PREC4: lo only on v0 strips) ----
  gemm7<0, 1, 1, 2, 768, 64><<<dim3(250), 512, 0, stream>>>(
      I, nullptr, nullptr, nullptr, W0h, W0l, Bf[0], nullptr,
      q0, nullptr, psum0, psq0, 256, 256, 0, 1);
  bn1(psum0, psq0, Gf[0], Zf[0], ss + 0 * 768, 250, 256, 1.f / 16000.f);
  gemm7<1, 6, 1, 4, 768, 64><<<dim3(1500), 512, 0, stream>>>(
      nullptr, X, TE, SE, KVQh, KVQl, b124, nullptr,
      kv0, q1, psum0, psq0, 768, 0, 0, 3);
  bn_part<<<dim3(64, 12), 512, 0, stream>>>(psum0, psq0, pp, 1500, 768);
  bn_fin2<<<dim3(8), 64, 0, stream>>>(pp, Gf[1], Zf[1], Gf[2], Zf[2], ssC, 768, 1.f / 96000.f);
  bn_fin<<<dim3(4), 64, 0, stream>>>(pp, Gf[4], Zf[4], ss + 4 * 768, 768, 512, 1.f / 96000.f);

  // ---- attn0 (single launch) -> o0b bf16 ----
  attn_sm<12, 32><<<dim3(500, 16), 512, 0, stream>>>(
      q0, kv0, kv0 + 256, ss + 0 * 768, ssC, ssC + 256, o0b,
      0, (size_t)6000 * 512, (size_t)16000 * 256, 512);

  // ---- m0o stats (one pass, PREC1, BM64) ----
  gemm7<2, 0, 1, 1, 256, 64><<<dim3(4000), 512, 0, stream>>>(
      o0b, nullptr, nullptr, nullptr, W3h, W3l, Bf[3], nullptr,
      nullptr, nullptr, psum0, psq0, 768, 768, 0, 3);
  bn1(psum0, psq0, Gf[3], Zf[3], ss + 3 * 768, 4000, 768, 1.f / 256000.f);

  // ---- pass B: per 2-batch chunk: H (BM64) -> fused k1|v1 (BM64) ----
  for (int cb = 0; cb < 8; ++cb) {
    const size_t oCh = (size_t)cb * 32000 * 256;
    gemm7<2, 2, 0, 2, 256, 64><<<dim3(500), 512, 0, stream>>>(
        o0b + oCh, nullptr, nullptr, nullptr, W3h, W3l, Bf[3], ss + 3 * 768,
        Hc, nullptr, nullptr, nullptr, 768, 768, 0, 3);
    gemm7<2, 5, 0, 3, 768, 64><<<dim3(500), 512, 0, stream>>>(
        Hc, nullptr, nullptr, nullptr, KV1h, KV1l, b56, nullptr,
        k1 + oCh, v1 + oCh, nullptr, nullptr, 512, 256, 0, 2);
  }

  // ---- m1k / m1v stats from stored raw k1 / v1 ----
  colstats<<<dim3(125), 256, 0, stream>>>(k1, psumK, psqK);
  bn1(psumK, psqK, Gf[5], Zf[5], ss + 5 * 768, 125, 256, 1.f / 256000.f);
  colstats<<<dim3(125), 256, 0, stream>>>(v1, psumK, psqK);
  bn1(psumK, psqK, Gf[6], Zf[6], ss + 6 * 768, 125, 256, 1.f / 256000.f);

  // ---- attn1 (single launch) -> o1 bf16 in d_out upper half ----
  attn_sm<32, 12><<<dim3(500, 16), 192, 0, stream>>>(
      q1, k1, v1, ss + 4 * 768, ss + 5 * 768, ss + 6 * 768, o1,
      (size_t)6000 * 256, (size_t)16000 * 256, (size_t)6000 * 256, 256);

  // ---- m1o -> y7 bf16 (BM64) ----
  gemm7<2, 1, 1, 2, 256, 64><<<dim3(1500), 512, 0, stream>>>(
      o1, nullptr, nullptr, nullptr, W7h, W7l, Bf[7], nullptr,
      y7, nullptr, psum0, psq0, 256, 256, 0, 1);
  bn1(psum0, psq0, Gf[7], Zf[7], ss + 7 * 768, 1500, 256, 1.f / 96000.f);
  bn_relu_addx<<<dim3(12000), 256, 0, stream>>>(y7, ss + 7 * 768, X, (float*)d_out);
}

// Round 21
// 2389.919 us; speedup vs baseline: 1.2778x; 1.0031x over previous
//
#include <hip/hip_runtime.h>
#include <stdint.h>

typedef __bf16 bf16_t;
typedef bf16_t bf16x8 __attribute__((ext_vector_type(8)));
typedef float f32x4 __attribute__((ext_vector_type(4)));

__device__ __forceinline__ float bf2f(unsigned short u) {
  union { unsigned int i; float f; } x; x.i = ((unsigned int)u) << 16; return x.f;
}
__device__ __forceinline__ unsigned short f2bf(float f) {
  union { float f; unsigned int i; } x; x.f = f;
  unsigned int r = x.i + 0x7FFFu + ((x.i >> 16) & 1u);
  return (unsigned short)(r >> 16);
}
__device__ __forceinline__ unsigned pack2(float a, float b) {
  return (unsigned)f2bf(a) | ((unsigned)f2bf(b) << 16);
}

__global__ void cat3(const float* __restrict__ a, const float* __restrict__ b,
                     const float* __restrict__ c, float* __restrict__ dst) {
  int i = threadIdx.x;
  dst[i] = a[i]; dst[256 + i] = b[i]; dst[512 + i] = c[i];
}

__global__ __launch_bounds__(256) void wsplit(
    const float* __restrict__ in, unsigned short* __restrict__ hi,
    unsigned short* __restrict__ lo, int n) {
  int i = (blockIdx.x * 256 + threadIdx.x) * 8;
  if (i >= n) return;
  float4 a = *(const float4*)(in + i);
  float4 b = *(const float4*)(in + i + 4);
  float f[8] = {a.x, a.y, a.z, a.w, b.x, b.y, b.z, b.w};
  unsigned short sh[8], sl[8];
#pragma unroll
  for (int j = 0; j < 8; ++j) {
    sh[j] = f2bf(f[j]);
    sl[j] = f2bf(f[j] - bf2f(sh[j]));
  }
  *(uint4*)(hi + i) = *(uint4*)sh;
  *(uint4*)(lo + i) = *(uint4*)sl;
}

struct f8 { float4 a, b; };

__device__ __forceinline__ f8 ld_c8(const float* __restrict__ X,
                                    const float* __restrict__ TE,
                                    const float* __restrict__ SE,
                                    size_t row, int cc) {
  const float* src = (cc < 256) ? X : ((cc < 512) ? TE : SE);
  const float* p = src + row * 256 + (cc & 255);
  f8 r; r.a = *(const float4*)p; r.b = *(const float4*)(p + 4);
  return r;
}
__device__ __forceinline__ uint4 pack_hi(const float4 a, const float4 b) {
  return make_uint4(pack2(a.x, a.y), pack2(a.z, a.w), pack2(b.x, b.y), pack2(b.z, b.w));
}

// ---------- gemm7: A-panel-resident GEMM, 8 waves, 32 cols/wave, BM rows ----
// A panel staged to LDS once (bf16 hi, XOR-swizzled); column pass = 256 cols
// (wave strips at +0/+128); B in registers, 128-K batches; no K-loop barriers
// (waves phase-shift freely -> T5 setprio arbitration around MFMA clusters).
// AMODE 0: A fp32. 1: A concat(X,TE,SE) fp32. 2: A bf16 raw.
// PREC 1: hi only. 2: hi+lo. 3: lo for strips >=256 (kv1: v1 cols).
//      4: lo for strips in [256,512) (fused kvq: v0 cols).
// SMODE 0: none, 1: raw bf16, 2: relu(BN) bf16,
//   5: dual raw bf16 (strip<256 -> Cb else Cb2, both stride 256),
//   6: tri raw bf16 (strip<512 -> Cb stride 512; else Cb2 stride 256).
// PART: per-block column partials (width Cout); cstr = C row stride.
template<int AMODE, int SMODE, int PART, int PREC, int K, int BM>
__global__ __launch_bounds__(512) void gemm7(
    const void* __restrict__ Ap, const float* __restrict__ AX,
    const float* __restrict__ ATE, const float* __restrict__ ASE,
    const unsigned short* __restrict__ Wh, const unsigned short* __restrict__ Wl,
    const float* __restrict__ bias, const float2* __restrict__ ssO,
    unsigned short* __restrict__ Cb, unsigned short* __restrict__ Cb2,
    float* __restrict__ psum, float* __restrict__ psq,
    int Cout, int cstr, int pOff, int nx) {
  constexpr int ASH = BM * K;
  constexpr int TOT = ASH + (SMODE != 0 ? BM * 136 : 8);
  constexpr int NC = K / 128;
  constexpr int MR = BM / 16;
  __shared__ unsigned short lds[TOT];
  unsigned short* lA = lds;
  unsigned short* lC = lds + ASH;

  const int tid = threadIdx.x;
  const int lane = tid & 63, wid = tid >> 6;
  const int l15 = lane & 15, l4 = lane >> 4;
  const int brow = blockIdx.x * BM;

  constexpr int CPR = K / 8;
#pragma unroll
  for (int i = 0; i < (BM * CPR) / 512; ++i) {
    int ch = i * 512 + tid;
    int row = ch / CPR, c8 = (ch % CPR) * 8;
    uint4 hv;
    if constexpr (AMODE == 2) {
      hv = *(const uint4*)((const unsigned short*)Ap + (size_t)(brow + row) * K + c8);
    } else if constexpr (AMODE == 0) {
      const float* p = (const float*)Ap + (size_t)(brow + row) * K + c8;
      hv = pack_hi(*(const float4*)p, *(const float4*)(p + 4));
    } else {
      f8 v = ld_c8(AX, ATE, ASE, (size_t)(brow + row), c8);
      hv = pack_hi(v.a, v.b);
    }
    int dst = row * K + (c8 & ~63) + ((c8 & 63) ^ ((row & 7) << 3));
    *(uint4*)(lA + dst) = hv;
  }
  __syncthreads();

  const int axor = (l15 & 7) << 3;
  const int colL = wid * 16 + l15;

  for (int cx = 0; cx < nx; ++cx) {
    const int bcol = cx * 256;
    const int bcs0 = bcol, bcs1 = bcol + 128;
    const bool lo0 = (PREC == 2) || (PREC == 3 && bcs0 >= 256) ||
                     (PREC == 4 && bcs0 >= 256 && bcs0 < 512);
    const bool lo1 = (PREC == 2) || (PREC == 3 && bcs1 >= 256) ||
                     (PREC == 4 && bcs1 >= 256 && bcs1 < 512);
    const unsigned short* wH0 = Wh + (size_t)(bcol + colL) * K + l4 * 8;
    const unsigned short* wH1 = wH0 + (size_t)128 * K;
    const unsigned short* wL0 = nullptr;
    const unsigned short* wL1 = nullptr;
    if constexpr (PREC >= 2) {
      wL0 = Wl + (size_t)(bcol + colL) * K + l4 * 8;
      wL1 = wL0 + (size_t)128 * K;
    }
    f32x4 acc[MR][2] = {};

#pragma unroll
    for (int c = 0; c < NC; ++c) {
      uint4 bh0[4], bh1[4], bl0[4], bl1[4];
#pragma unroll
      for (int ks = 0; ks < 4; ++ks) {
        bh0[ks] = *(const uint4*)(wH0 + c * 128 + ks * 32);
        bh1[ks] = *(const uint4*)(wH1 + c * 128 + ks * 32);
      }
      if constexpr (PREC >= 2) {
        if (lo0) {
#pragma unroll
          for (int ks = 0; ks < 4; ++ks) bl0[ks] = *(const uint4*)(wL0 + c * 128 + ks * 32);
        }
        if (lo1) {
#pragma unroll
          for (int ks = 0; ks < 4; ++ks) bl1[ks] = *(const uint4*)(wL1 + c * 128 + ks * 32);
        }
      }
#pragma unroll
      for (int kk = 0; kk < 4; ++kk) {
        const int kabs = c * 128 + kk * 32;
        const int kt64 = kabs & ~63;
        const int cofs = ((kabs & 32) + l4 * 8) ^ axor;
        bf16x8 af[MR];
#pragma unroll
        for (int m = 0; m < MR; ++m)
          af[m] = *(const bf16x8*)(lA + (m * 16 + l15) * K + kt64 + cofs);
        bf16x8 b0 = *(const bf16x8*)&bh0[kk];
        bf16x8 b1 = *(const bf16x8*)&bh1[kk];
        __builtin_amdgcn_s_setprio(1);   // T5: favor MFMA-phase waves
#pragma unroll
        for (int m = 0; m < MR; ++m) {
          acc[m][0] = __builtin_amdgcn_mfma_f32_16x16x32_bf16(af[m], b0, acc[m][0], 0, 0, 0);
          acc[m][1] = __builtin_amdgcn_mfma_f32_16x16x32_bf16(af[m], b1, acc[m][1], 0, 0, 0);
        }
        if constexpr (PREC >= 2) {
          if (lo0) {
            bf16x8 c0 = *(const bf16x8*)&bl0[kk];
#pragma unroll
            for (int m = 0; m < MR; ++m)
              acc[m][0] = __builtin_amdgcn_mfma_f32_16x16x32_bf16(af[m], c0, acc[m][0], 0, 0, 0);
          }
          if (lo1) {
            bf16x8 c1 = *(const bf16x8*)&bl1[kk];
#pragma unroll
            for (int m = 0; m < MR; ++m)
              acc[m][1] = __builtin_amdgcn_mfma_f32_16x16x32_bf16(af[m], c1, acc[m][1], 0, 0, 0);
          }
        }
        __builtin_amdgcn_s_setprio(0);
      }
    }

#pragma unroll
    for (int s = 0; s < 2; ++s) {
      const int bcs = bcol + s * 128;
      const int col = bcs + colL;
      float cs = 0.f, cq = 0.f;
      float bv = bias[col];
      float2 s2 = make_float2(1.f, 0.f);
      if constexpr (SMODE == 2) s2 = ssO[col];
      if constexpr (SMODE != 0) __syncthreads();
#pragma unroll
      for (int m = 0; m < MR; ++m) {
#pragma unroll
        for (int r = 0; r < 4; ++r) {
          float v = acc[m][s][r] + bv;
          if constexpr (PART) { cs += v; cq += v * v; }
          if constexpr (SMODE == 2) v = fmaxf(v * s2.x + s2.y, 0.f);
          if constexpr (SMODE != 0) lC[(m * 16 + l4 * 4 + r) * 136 + colL] = f2bf(v);
        }
      }
      if constexpr (SMODE != 0) {
        __syncthreads();
        const int rw = tid >> 4, c16 = (tid & 15) * 8;
#pragma unroll
        for (int it = 0; it < BM / 32; ++it) {
          int rr = it * 32 + rw;
          uint4 val = *(const uint4*)(lC + rr * 136 + c16);
          if constexpr (SMODE == 5) {
            unsigned short* dst = (bcs < 256) ? Cb : Cb2;
            *(uint4*)(dst + (size_t)(brow + rr) * 256 + (bcs & 255) + c16) = val;
          } else if constexpr (SMODE == 6) {
            if (bcs < 512)
              *(uint4*)(Cb + (size_t)(brow + rr) * 512 + bcs + c16) = val;
            else
              *(uint4*)(Cb2 + (size_t)(brow + rr) * 256 + (bcs - 512) + c16) = val;
          } else {
            *(uint4*)(Cb + (size_t)(brow + rr) * cstr + bcs + c16) = val;
          }
        }
      }
      if constexpr (PART) {
        cs += __shfl_xor(cs, 16); cs += __shfl_xor(cs, 32);
        cq += __shfl_xor(cq, 16); cq += __shfl_xor(cq, 32);
        if (l4 == 0) {
          size_t pidx = (size_t)(pOff + blockIdx.x) * Cout + col;
          psum[pidx] = cs;
          psq[pidx]  = cq;
        }
      }
    }
  }
}

// ---------- column stats of a bf16 [rows][256] tensor; 2048 rows/block ----------
__global__ __launch_bounds__(256) void colstats(
    const unsigned short* __restrict__ A, float* __restrict__ psum,
    float* __restrict__ psq) {
  const int tid = threadIdx.x;
  const int r8 = tid >> 5, co = tid & 31;
  float s[8] = {0,0,0,0,0,0,0,0}, q[8] = {0,0,0,0,0,0,0,0};
  size_t base = (size_t)blockIdx.x * 2048;
  for (int it = 0; it < 256; ++it) {
    size_t row = base + it * 8 + r8;
    uint4 v = *(const uint4*)(A + row * 256 + co * 8);
    const unsigned short* pv = (const unsigned short*)&v;
#pragma unroll
    for (int j = 0; j < 8; ++j) {
      float f = bf2f(pv[j]);
      s[j] += f; q[j] += f * f;
    }
  }
  __shared__ float ls[8][32][8], lq[8][32][8];
#pragma unroll
  for (int j = 0; j < 8; ++j) { ls[r8][co][j] = s[j]; lq[r8][co][j] = q[j]; }
  __syncthreads();
  int co2 = tid >> 3, j2 = tid & 7;
  float S = 0.f, Q = 0.f;
#pragma unroll
  for (int r = 0; r < 8; ++r) { S += ls[r][co2][j2]; Q += lq[r][co2][j2]; }
  psum[(size_t)blockIdx.x * 256 + co2 * 8 + j2] = S;
  psq [(size_t)blockIdx.x * 256 + co2 * 8 + j2] = Q;
}

// ---------- BN stats: row-parallel partial + finalize ----------
__global__ __launch_bounds__(512) void bn_part(
    const float* __restrict__ psum, const float* __restrict__ psq,
    float* __restrict__ pp, int gridM, int Cout) {
  const int lane = threadIdx.x & 63, wv = threadIdx.x >> 6;
  const int c = blockIdx.y * 64 + lane;
  float s = 0.f, q = 0.f;
  for (int r = blockIdx.x + 64 * wv; r < gridM; r += 512) {
    s += psum[(size_t)r * Cout + c];
    q += psq[(size_t)r * Cout + c];
  }
  __shared__ float rs[8][64], rq[8][64];
  rs[wv][lane] = s; rq[wv][lane] = q;
  __syncthreads();
  if (threadIdx.x < 64) {
    float S = 0.f, Q = 0.f;
#pragma unroll
    for (int w2 = 0; w2 < 8; ++w2) { S += rs[w2][threadIdx.x]; Q += rq[w2][threadIdx.x]; }
    pp[(size_t)blockIdx.x * Cout + blockIdx.y * 64 + threadIdx.x] = S;
    pp[(size_t)(64 + blockIdx.x) * Cout + blockIdx.y * 64 + threadIdx.x] = Q;
  }
}
__global__ __launch_bounds__(64) void bn_fin(
    const float* __restrict__ pp, const float* __restrict__ g,
    const float* __restrict__ be, float2* __restrict__ ss,
    int CoutT, int colOff, float invR) {
  int c = blockIdx.x * 64 + threadIdx.x;
  int cp = colOff + c;
  float S = 0.f, Q = 0.f;
  for (int r = 0; r < 64; ++r) {
    S += pp[(size_t)r * CoutT + cp];
    Q += pp[(size_t)(64 + r) * CoutT + cp];
  }
  float mu = S * invR, var = Q * invR - mu * mu;
  float sc = g[c] * rsqrtf(var + 1e-5f);
  ss[c] = make_float2(sc, be[c] - mu * sc);
}
__global__ __launch_bounds__(64) void bn_fin2(
    const float* __restrict__ pp, const float* __restrict__ gA,
    const float* __restrict__ zA, const float* __restrict__ gB,
    const float* __restrict__ zB, float2* __restrict__ ssC,
    int CoutT, float invR) {
  int c = blockIdx.x * 64 + threadIdx.x;
  float S = 0.f, Q = 0.f;
  for (int r = 0; r < 64; ++r) {
    S += pp[(size_t)r * CoutT + c];
    Q += pp[(size_t)(64 + r) * CoutT + c];
  }
  float mu = S * invR, var = Q * invR - mu * mu;
  const float* g = (c < 256) ? gA : gB;
  const float* z = (c < 256) ? zA : zB;
  int ci = c & 255;
  float sc = g[ci] * rsqrtf(var + 1e-5f);
  ssC[c] = make_float2(sc, z[ci] - mu * sc);
}

// ---------- attention: q bf16 (+BN), k/v bf16 (+BN), bf16 out ----------
template<int NK, int NQ>
__global__ void attn_sm(const unsigned short* __restrict__ qy,
                        const unsigned short* __restrict__ ky,
                        const unsigned short* __restrict__ vy,
                        const float2* __restrict__ ssq, const float2* __restrict__ ssk,
                        const float2* __restrict__ ssv, unsigned short* __restrict__ out,
                        size_t qStride, size_t kvStride, size_t oStride, int RS) {
  __shared__ float kl[NK][16][17];
  __shared__ float vl[NK][16][17];
  const int n = blockIdx.x, b = blockIdx.y;
  const int tid = threadIdx.x;
  const unsigned short* kyb = ky + (size_t)b * kvStride;
  const unsigned short* vyb = vy + (size_t)b * kvStride;
  for (int ch = tid; ch < NK * 32; ch += NQ * 16) {
    int t = ch >> 5, c8 = (ch & 31) * 8;
    size_t src = ((size_t)t * 500 + n) * RS + c8;
    uint4 kv = *(const uint4*)(kyb + src);
    uint4 vv = *(const uint4*)(vyb + src);
    const unsigned short* kp = (const unsigned short*)&kv;
    const unsigned short* vp = (const unsigned short*)&vv;
#pragma unroll
    for (int j = 0; j < 8; ++j) {
      int c = c8 + j;
      float2 sk = ssk[c], sv = ssv[c];
      kl[t][c >> 4][c & 15] = fmaxf(bf2f(kp[j]) * sk.x + sk.y, 0.f);
      vl[t][c >> 4][c & 15] = fmaxf(bf2f(vp[j]) * sv.x + sv.y, 0.f);
    }
  }
  __syncthreads();
  const int s = tid >> 4, h = tid & 15;
  unsigned short qraw[16];
  size_t qb = (size_t)b * qStride + ((size_t)s * 500 + n) * 256 + h * 16;
  *(uint4*)qraw = *(const uint4*)(qy + qb);
  *(uint4*)(qraw + 8) = *(const uint4*)(qy + qb + 8);
  float qv[16];
#pragma unroll
  for (int c = 0; c < 16; ++c) {
    float2 sq = ssq[h * 16 + c];
    qv[c] = fmaxf(bf2f(qraw[c]) * sq.x + sq.y, 0.f);
  }
  float lg[NK], mx = -1e30f;
#pragma unroll
  for (int t = 0; t < NK; ++t) {
    float d = 0.f;
#pragma unroll
    for (int c = 0; c < 16; ++c) d += qv[c] * kl[t][h][c];
    lg[t] = d * 0.25f;
    mx = fmaxf(mx, lg[t]);
  }
  float sum = 0.f;
#pragma unroll
  for (int t = 0; t < NK; ++t) { lg[t] = __expf(lg[t] - mx); sum += lg[t]; }
  float inv = 1.f / sum;
  float o[16];
#pragma unroll
  for (int c = 0; c < 16; ++c) o[c] = 0.f;
#pragma unroll
  for (int t = 0; t < NK; ++t) {
    float p = lg[t] * inv;
#pragma unroll
    for (int c = 0; c < 16; ++c) o[c] += p * vl[t][h][c];
  }
  size_t ob = (size_t)b * oStride + ((size_t)s * 500 + n) * 256 + h * 16;
  uint4 w0;
  w0.x = pack2(o[0], o[1]); w0.y = pack2(o[2], o[3]);
  w0.z = pack2(o[4], o[5]); w0.w = pack2(o[6], o[7]);
  *(uint4*)(out + ob) = w0;
  w0.x = pack2(o[8], o[9]); w0.y = pack2(o[10], o[11]);
  w0.z = pack2(o[12], o[13]); w0.w = pack2(o[14], o[15]);
  *(uint4*)(out + ob + 8) = w0;
}

// ---------- final: out = X + relu(BN(y)), y bf16 ----------
__global__ __launch_bounds__(256) void bn_relu_addx(
    const unsigned short* __restrict__ y, const float2* __restrict__ ss,
    const float* __restrict__ X, float* __restrict__ out) {
  int r = blockIdx.x * 8 + (threadIdx.x >> 5);
  int c8 = (threadIdx.x & 31) * 8;
  size_t idx = (size_t)r * 256 + c8;
  uint4 yv4 = *(const uint4*)(y + idx);
  const unsigned short* yv = (const unsigned short*)&yv4;
  float4 x0 = *(const float4*)(X + idx);
  float4 x1 = *(const float4*)(X + idx + 4);
  float ov[8];
#pragma unroll
  for (int j = 0; j < 8; ++j) {
    float2 sc = ss[c8 + j];
    ov[j] = fmaxf(bf2f(yv[j]) * sc.x + sc.y, 0.f);
  }
  *(float4*)(out + idx)     = make_float4(x0.x + ov[0], x0.y + ov[1], x0.z + ov[2], x0.w + ov[3]);
  *(float4*)(out + idx + 4) = make_float4(x1.x + ov[4], x1.y + ov[5], x1.z + ov[6], x1.w + ov[7]);
}

// ---------- launcher ----------
extern "C" void kernel_launch(void* const* d_in, const int* in_sizes, int n_in,
                              void* d_out, int out_size, void* d_ws, size_t ws_size,
                              hipStream_t stream) {
  (void)in_sizes; (void)n_in; (void)out_size; (void)ws_size;
  const float* X  = (const float*)d_in[0];
  const float* TE = (const float*)d_in[1];
  const float* SE = (const float*)d_in[2];
  const float* I  = (const float*)d_in[3];
  const float *Wf[8], *Bf[8], *Gf[8], *Zf[8];
  for (int l = 0; l < 8; ++l) {
    Wf[l] = (const float*)d_in[4 + l * 4 + 0];
    Bf[l] = (const float*)d_in[4 + l * 4 + 1];
    Gf[l] = (const float*)d_in[4 + l * 4 + 2];
    Zf[l] = (const float*)d_in[4 + l * 4 + 3];
  }

  char* w = (char*)d_ws;
  size_t off = 0;
  auto alloc = [&](size_t bytes) -> void* {
    void* p = w + off;
    off += (bytes + 255) & ~(size_t)255;
    return p;
  };

  // ---- workspace (~342 MB; ws >= 345 MB proven) ----
  float* psum0 = (float*)alloc((size_t)4000 * 768 * 4);
  float* psq0  = (float*)alloc((size_t)4000 * 768 * 4);
  float* psumK = (float*)alloc((size_t)125 * 256 * 4);
  float* psqK  = (float*)alloc((size_t)125 * 256 * 4);
  float* pp    = (float*)alloc((size_t)128 * 768 * 4);
  float2* ss   = (float2*)alloc((size_t)(8 * 768 + 512) * sizeof(float2));
  float2* ssC  = ss + 8 * 768;
  unsigned short *W0h, *W0l, *W3h, *W3l, *W7h, *W7l;
  unsigned short *KVQh, *KVQl, *KV1h, *KV1l;
  W0h = (unsigned short*)alloc(196608 * 2); W0l = (unsigned short*)alloc(196608 * 2);
  W3h = (unsigned short*)alloc(196608 * 2); W3l = (unsigned short*)alloc(196608 * 2);
  W7h = (unsigned short*)alloc(65536 * 2);  W7l = (unsigned short*)alloc(65536 * 2);
  KVQh = (unsigned short*)alloc(589824 * 2); KVQl = (unsigned short*)alloc(589824 * 2);
  KV1h = (unsigned short*)alloc(393216 * 2); KV1l = (unsigned short*)alloc(393216 * 2);
  float* b124 = (float*)alloc(768 * 4);
  float* b56  = (float*)alloc(512 * 4);
  // region R: q0 | kv0 | pad  == exactly k1 [256000][256] bf16 later
  char* R = (char*)alloc(131072000);
  unsigned short* q0  = (unsigned short*)R;                    // 16000*256
  unsigned short* kv0 = (unsigned short*)(R + 8192000);        // 96000*512
  unsigned short* k1  = (unsigned short*)R;                    // 256000*256
  unsigned short* o0b = (unsigned short*)alloc(131072000);     // 256000*256 -> v1 -> y7
  unsigned short* v1  = o0b;
  unsigned short* y7  = o0b;
  unsigned short* Hc  = (unsigned short*)alloc((size_t)32000 * 768 * 2);  // 2-batch chunk

  unsigned short* q1 = (unsigned short*)d_out;                 // bf16 (lower half)
  unsigned short* o1 = (unsigned short*)d_out + 24576000;      // bf16 (upper half)

  // ---- prep ----
  cat3<<<dim3(1), 256, 0, stream>>>(Bf[1], Bf[2], Bf[4], b124);
  cat3<<<dim3(1), 256, 0, stream>>>(Bf[5], Bf[6], Bf[6], b56);  // only first 512 used
  wsplit<<<dim3(96), 256, 0, stream>>>(Wf[0], W0h, W0l, 196608);
  wsplit<<<dim3(96), 256, 0, stream>>>(Wf[3], W3h, W3l, 196608);
  wsplit<<<dim3(32), 256, 0, stream>>>(Wf[7], W7h, W7l, 65536);
  wsplit<<<dim3(96), 256, 0, stream>>>(Wf[1], KVQh, KVQl, 196608);
  wsplit<<<dim3(96), 256, 0, stream>>>(Wf[2], KVQh + 196608, KVQl + 196608, 196608);
  wsplit<<<dim3(96), 256, 0, stream>>>(Wf[4], KVQh + 393216, KVQl + 393216, 196608);
  wsplit<<<dim3(96), 256, 0, stream>>>(Wf[5], KV1h, KV1l, 196608);
  wsplit<<<dim3(96), 256, 0, stream>>>(Wf[6], KV1h + 196608, KV1l + 196608, 196608);

  auto bn1 = [&](float* ps, float* pq, const float* g, const float* z, float2* dst,
                 int gridM, int Cout, float invR) {
    bn_part<<<dim3(64, Cout / 64), 512, 0, stream>>>(ps, pq, pp, gridM, Cout);
    bn_fin<<<dim3(Cout / 64), 64, 0, stream>>>(pp, g, z, dst, Cout, 0, invR);
  };

  // ---- stage 1: q0, fused k0|v0|q1 (BM64, PREC4: lo only on v0 strips) ----
  gemm7<0, 1, 1, 2, 768, 64><<<dim3(250), 512, 0, stream>>>(
      I, nullptr, nullptr, nullptr, W0h, W0l, Bf[0], nullptr,
      q0, nullptr, psum0, psq0, 256, 256, 0, 1);
  bn1(psum0, psq0, Gf[0], Zf[0], ss + 0 * 768, 250, 256, 1.f / 16000.f);
  gemm7<1, 6, 1, 4, 768, 64><<<dim3(1500), 512, 0, stream>>>(
      nullptr, X, TE, SE, KVQh, KVQl, b124, nullptr,
      kv0, q1, psum0, psq0, 768, 0, 0, 3);
  bn_part<<<dim3(64, 12), 512, 0, stream>>>(psum0, psq0, pp, 1500, 768);
  bn_fin2<<<dim3(8), 64, 0, stream>>>(pp, Gf[1], Zf[1], Gf[2], Zf[2], ssC, 768, 1.f / 96000.f);
  bn_fin<<<dim3(4), 64, 0, stream>>>(pp, Gf[4], Zf[4], ss + 4 * 768, 768, 512, 1.f / 96000.f);

  // ---- attn0 (single launch) -> o0b bf16 ----
  attn_sm<12, 32><<<dim3(500, 16), 512, 0, stream>>>(
      q0, kv0, kv0 + 256, ss + 0 * 768, ssC, ssC + 256, o0b,
      0, (size_t)6000 * 512, (size_t)16000 * 256, 512);

  // ---- m0o stats (one pass, PREC1, BM64) ----
  gemm7<2, 0, 1, 1, 256, 64><<<dim3(4000), 512, 0, stream>>>(
      o0b, nullptr, nullptr, nullptr, W3h, W3l, Bf[3], nullptr,
      nullptr, nullptr, psum0, psq0, 768, 768, 0, 3);
  bn1(psum0, psq0, Gf[3], Zf[3], ss + 3 * 768, 4000, 768, 1.f / 256000.f);

  // ---- pass B: per 2-batch chunk: H (BM64) -> fused k1|v1 (BM64) ----
  for (int cb = 0; cb < 8; ++cb) {
    const size_t oCh = (size_t)cb * 32000 * 256;
    gemm7<2, 2, 0, 2, 256, 64><<<dim3(500), 512, 0, stream>>>(
        o0b + oCh, nullptr, nullptr, nullptr, W3h, W3l, Bf[3], ss + 3 * 768,
        Hc, nullptr, nullptr, nullptr, 768, 768, 0, 3);
    gemm7<2, 5, 0, 3, 768, 64><<<dim3(500), 512, 0, stream>>>(
        Hc, nullptr, nullptr, nullptr, KV1h, KV1l, b56, nullptr,
        k1 + oCh, v1 + oCh, nullptr, nullptr, 512, 256, 0, 2);
  }

  // ---- m1k / m1v stats from stored raw k1 / v1 ----
  colstats<<<dim3(125), 256, 0, stream>>>(k1, psumK, psqK);
  bn1(psumK, psqK, Gf[5], Zf[5], ss + 5 * 768, 125, 256, 1.f / 256000.f);
  colstats<<<dim3(125), 256, 0, stream>>>(v1, psumK, psqK);
  bn1(psumK, psqK, Gf[6], Zf[6], ss + 6 * 768, 125, 256, 1.f / 256000.f);

  // ---- attn1 (single launch) -> o1 bf16 in d_out upper half ----
  attn_sm<32, 12><<<dim3(500, 16), 192, 0, stream>>>(
      q1, k1, v1, ss + 4 * 768, ss + 5 * 768, ss + 6 * 768, o1,
      (size_t)6000 * 256, (size_t)16000 * 256, (size_t)6000 * 256, 256);

  // ---- m1o -> y7 bf16 (BM64) ----
  gemm7<2, 1, 1, 2, 256, 64><<<dim3(1500), 512, 0, stream>>>(
      o1, nullptr, nullptr, nullptr, W7h, W7l, Bf[7], nullptr,
      y7, nullptr, psum0, psq0, 256, 256, 0, 1);
  bn1(psum0, psq0, Gf[7], Zf[7], ss + 7 * 768, 1500, 256, 1.f / 96000.f);
  bn_relu_addx<<<dim3(12000), 256, 0, stream>>>(y7, ss + 7 * 768, X, (float*)d_out);
}